// Round 5
// baseline (621.516 us; speedup 1.0000x reference)
//
#include <hip/hip_runtime.h>

#define N_NODES 50000
#define N_EDGES 800000
#define C 128
#define N_GRAPHS 512
#define OUTDIM 5
#define BN_EPS 1e-5f
#define NB_SCAN 196   // ceil(50000/256)
#define RT 782        // ceil(50000/64) row tiles

// ================= CSR build =================
__global__ __launch_bounds__(256) void hist_kernel(const int* __restrict__ ei,
                                                   int* __restrict__ deg)
{
    int e = blockIdx.x * 256 + threadIdx.x;
    atomicAdd(&deg[ei[N_EDGES + e]], 1);
}

__global__ __launch_bounds__(256) void scan1_kernel(const int* __restrict__ deg,
                                                    int* __restrict__ rowptr,
                                                    int* __restrict__ bsum)
{
    __shared__ int sh[256];
    int tid = threadIdx.x;
    int i = blockIdx.x * 256 + tid;
    int v = (i < N_NODES) ? deg[i] : 0;
    sh[tid] = v;
    __syncthreads();
    #pragma unroll
    for (int off = 1; off < 256; off <<= 1) {
        int t = (tid >= off) ? sh[tid - off] : 0;
        __syncthreads();
        sh[tid] += t;
        __syncthreads();
    }
    if (i < N_NODES) rowptr[i] = sh[tid] - v;
    if (tid == 255) bsum[blockIdx.x] = sh[255];
}

__global__ __launch_bounds__(256) void scan2_kernel(int* __restrict__ bsum)
{
    __shared__ int sh[256];
    int tid = threadIdx.x;
    int v = (tid < NB_SCAN) ? bsum[tid] : 0;
    sh[tid] = v;
    __syncthreads();
    #pragma unroll
    for (int off = 1; off < 256; off <<= 1) {
        int t = (tid >= off) ? sh[tid - off] : 0;
        __syncthreads();
        sh[tid] += t;
        __syncthreads();
    }
    if (tid < NB_SCAN) bsum[tid] = sh[tid] - v;
}

__global__ __launch_bounds__(256) void scan3_kernel(const int* __restrict__ bsum,
                                                    int* __restrict__ rowptr,
                                                    int* __restrict__ cursor)
{
    int i = blockIdx.x * 256 + threadIdx.x;
    if (i < N_NODES) {
        int v = rowptr[i] + bsum[blockIdx.x];
        rowptr[i] = v;
        cursor[i] = v;
    }
    if (i == 0) rowptr[N_NODES] = N_EDGES;
}

__global__ __launch_bounds__(256) void scatter_kernel(const int* __restrict__ ei,
                                                      const float* __restrict__ ew,
                                                      int* __restrict__ cursor,
                                                      float2* __restrict__ csr)
{
    int e = blockIdx.x * 256 + threadIdx.x;
    int dst = ei[N_EDGES + e];
    int pos = atomicAdd(&cursor[dst], 1);
    float2 ent;
    ent.x = __int_as_float(ei[e]);
    ent.y = ew[e];
    csr[pos] = ent;
}

// ================= atomic-free aggregation =================
__global__ __launch_bounds__(256) void aggr_kernel(const float* __restrict__ x,
                                                   const float2* __restrict__ csr,
                                                   const int* __restrict__ rowptr,
                                                   const float* __restrict__ We,
                                                   const float* __restrict__ be,
                                                   float* __restrict__ hout)
{
    int node = blockIdx.x * 4 + (threadIdx.x >> 6);
    int lane = threadIdx.x & 63;
    int c = lane * 2;
    float2 wev = *reinterpret_cast<const float2*>(&We[c]);
    float2 bev = *reinterpret_cast<const float2*>(&be[c]);
    int p  = rowptr[node];
    int p1 = rowptr[node + 1];
    float2 acc = *reinterpret_cast<const float2*>(&x[(size_t)node * C + c]);
    for (; p + 2 <= p1; p += 2) {
        float2 e0 = csr[p], e1 = csr[p + 1];
        int s0 = __float_as_int(e0.x), s1 = __float_as_int(e1.x);
        float2 xa = *reinterpret_cast<const float2*>(&x[(size_t)s0 * C + c]);
        float2 xb = *reinterpret_cast<const float2*>(&x[(size_t)s1 * C + c]);
        float m;
        m = xa.x + e0.y * wev.x + bev.x; acc.x += fmaxf(m, 0.f);
        m = xa.y + e0.y * wev.y + bev.y; acc.y += fmaxf(m, 0.f);
        m = xb.x + e1.y * wev.x + bev.x; acc.x += fmaxf(m, 0.f);
        m = xb.y + e1.y * wev.y + bev.y; acc.y += fmaxf(m, 0.f);
    }
    if (p < p1) {
        float2 e0 = csr[p];
        int s0 = __float_as_int(e0.x);
        float2 xa = *reinterpret_cast<const float2*>(&x[(size_t)s0 * C + c]);
        float m;
        m = xa.x + e0.y * wev.x + bev.x; acc.x += fmaxf(m, 0.f);
        m = xa.y + e0.y * wev.y + bev.y; acc.y += fmaxf(m, 0.f);
    }
    *reinterpret_cast<float2*>(&hout[(size_t)node * C + c]) = acc;
}

// ================= register-tiled GEMM: 64x64 tile, 4x4 per thread =================
// MODE 0: out = A@W.T + bias
// MODE 1: h = relu(A*scale+shift); out = relu(h@W.T + bias)
// MODE 2: like MODE 1, but atomicMax-pool into out[batch[row]*C + col] (no dense store)
template<int MODE>
__global__ __launch_bounds__(256) void gemm_kernel(
    const float* __restrict__ A,
    const float* __restrict__ W,          // [128][128] row-major [col][k]
    const float* __restrict__ bias,
    const float* __restrict__ scale, const float* __restrict__ shift,
    const int* __restrict__ batch,
    float* __restrict__ out)
{
    __shared__ __align__(16) float hs[64 * 132];   // [row][k], pad 132
    __shared__ __align__(16) float wsD[64 * 132];  // [col][k ^ swz(col)], pad 132
    const int tid  = threadIdx.x;
    const int tile = blockIdx.x >> 1;
    const int cb   = (blockIdx.x & 1) << 6;        // col base: 0 or 64
    const int row0 = tile << 6;

    // ---- stage A tile (64 rows x 128 k), fused BN+ReLU for MODE>=1
    #pragma unroll
    for (int i = 0; i < 8; ++i) {
        int idx = tid + i * 256;                   // 2048 float4 quads
        int rr = idx >> 5;
        int cq = (idx & 31) << 2;
        int row = row0 + rr;
        float4 v = make_float4(0.f, 0.f, 0.f, 0.f);
        if (row < N_NODES) {
            v = *reinterpret_cast<const float4*>(&A[(size_t)row * C + cq]);
            if (MODE >= 1) {
                float4 sc = *reinterpret_cast<const float4*>(&scale[cq]);
                float4 sh = *reinterpret_cast<const float4*>(&shift[cq]);
                v.x = fmaxf(v.x * sc.x + sh.x, 0.f);
                v.y = fmaxf(v.y * sc.y + sh.y, 0.f);
                v.z = fmaxf(v.z * sc.z + sh.z, 0.f);
                v.w = fmaxf(v.w * sc.w + sh.w, 0.f);
            }
        }
        *reinterpret_cast<float4*>(&hs[rr * 132 + cq]) = v;
    }
    // ---- stage W slice (64 cols x 128 k) with k-XOR swizzle per col
    #pragma unroll
    for (int i = 0; i < 8; ++i) {
        int idx = tid + i * 256;
        int cc = idx >> 5;
        int kq = (idx & 31) << 2;
        float4 v = *reinterpret_cast<const float4*>(&W[(size_t)(cb + cc) * C + kq]);
        int m = ((cc >> 2) & 7) << 2;
        *reinterpret_cast<float4*>(&wsD[cc * 132 + (kq ^ m)]) = v;
    }
    __syncthreads();

    const int cgrp  = tid & 15;
    const int r0    = (tid >> 4) << 2;             // 0..60
    const int cl0   = cgrp << 2;                   // 0..60
    const int wmask = (cgrp & 7) << 2;             // swizzle for this thread's 4 cols

    float acc[4][4];
    #pragma unroll
    for (int j = 0; j < 4; ++j)
        #pragma unroll
        for (int i = 0; i < 4; ++i) acc[j][i] = 0.f;

    #pragma unroll 4
    for (int k0 = 0; k0 < 128; k0 += 4) {
        float4 ha[4], wb[4];
        #pragma unroll
        for (int j = 0; j < 4; ++j)
            ha[j] = *reinterpret_cast<const float4*>(&hs[(r0 + j) * 132 + k0]);
        int kx = k0 ^ wmask;
        #pragma unroll
        for (int i = 0; i < 4; ++i)
            wb[i] = *reinterpret_cast<const float4*>(&wsD[(cl0 + i) * 132 + kx]);
        #pragma unroll
        for (int j = 0; j < 4; ++j)
            #pragma unroll
            for (int i = 0; i < 4; ++i) {
                acc[j][i] += ha[j].x * wb[i].x;
                acc[j][i] += ha[j].y * wb[i].y;
                acc[j][i] += ha[j].z * wb[i].z;
                acc[j][i] += ha[j].w * wb[i].w;
            }
    }

    float4 bi = *reinterpret_cast<const float4*>(&bias[cb + cl0]);
    #pragma unroll
    for (int j = 0; j < 4; ++j) {
        int row = row0 + r0 + j;
        if (row < N_NODES) {
            float4 o;
            o.x = acc[j][0] + bi.x;
            o.y = acc[j][1] + bi.y;
            o.z = acc[j][2] + bi.z;
            o.w = acc[j][3] + bi.w;
            if (MODE >= 1) {
                o.x = fmaxf(o.x, 0.f); o.y = fmaxf(o.y, 0.f);
                o.z = fmaxf(o.z, 0.f); o.w = fmaxf(o.w, 0.f);
            }
            if (MODE == 2) {
                int g = batch[row];
                int* pp = reinterpret_cast<int*>(&out[(size_t)g * C + cb + cl0]);
                atomicMax(pp + 0, __float_as_int(o.x));
                atomicMax(pp + 1, __float_as_int(o.y));
                atomicMax(pp + 2, __float_as_int(o.z));
                atomicMax(pp + 3, __float_as_int(o.w));
            } else {
                *reinterpret_cast<float4*>(&out[(size_t)row * C + cb + cl0]) = o;
            }
        }
    }
}

// ================= BatchNorm stats =================
__global__ __launch_bounds__(256) void stats_kernel(const float* __restrict__ t,
                                                    float* __restrict__ gsum, float* __restrict__ gsq)
{
    int tid = threadIdx.x;
    int c = tid & 127;
    int half = tid >> 7;
    float s = 0.f, q = 0.f;
    for (int n = blockIdx.x * 2 + half; n < N_NODES; n += gridDim.x * 2) {
        float v = t[(size_t)n * C + c];
        s += v; q += v * v;
    }
    __shared__ float ls[256];
    ls[tid] = s; __syncthreads();
    if (tid < 128) unsafeAtomicAdd(&gsum[tid], ls[tid] + ls[tid + 128]);
    __syncthreads();
    ls[tid] = q; __syncthreads();
    if (tid < 128) unsafeAtomicAdd(&gsq[tid], ls[tid] + ls[tid + 128]);
}

__global__ void bnfin_kernel(const float* __restrict__ gsum, const float* __restrict__ gsq,
                             const float* __restrict__ g, const float* __restrict__ bt,
                             float* __restrict__ scale, float* __restrict__ shift)
{
    int c = threadIdx.x;
    float mu  = gsum[c] * (1.f / N_NODES);
    float var = gsq[c] * (1.f / N_NODES) - mu * mu;
    float rs  = rsqrtf(var + BN_EPS);
    float sc  = rs * g[c];
    scale[c] = sc;
    shift[c] = bt[c] - mu * sc;
}

// ================= final linear =================
__global__ __launch_bounds__(64) void final_kernel(const float* __restrict__ pooled,
                                                   const float* __restrict__ lw,
                                                   const float* __restrict__ lb,
                                                   float* __restrict__ out)
{
    int gph = blockIdx.x;
    int lane = threadIdx.x;
    float v0 = pooled[(size_t)gph * C + lane];
    float v1 = pooled[(size_t)gph * C + lane + 64];
    for (int o = 0; o < OUTDIM; ++o) {
        float p = v0 * lw[o * C + lane] + v1 * lw[o * C + lane + 64];
        #pragma unroll
        for (int off = 32; off > 0; off >>= 1) p += __shfl_down(p, off);
        if (lane == 0) out[gph * OUTDIM + o] = p + lb[o];
    }
}

extern "C" void kernel_launch(void* const* d_in, const int* in_sizes, int n_in,
                              void* d_out, int out_size, void* d_ws, size_t ws_size,
                              hipStream_t stream)
{
    const float* x0   = (const float*)d_in[0];
    const int*   ei   = (const int*)  d_in[1];
    const float* ew   = (const float*)d_in[2];
    const int*   batch= (const int*)  d_in[3];
    const float* We0  = (const float*)d_in[4];
    const float* be0  = (const float*)d_in[5];
    const float* W1_0 = (const float*)d_in[6];
    const float* b1_0 = (const float*)d_in[7];
    const float* g0   = (const float*)d_in[8];
    const float* bt0  = (const float*)d_in[9];
    const float* W2_0 = (const float*)d_in[10];
    const float* b2_0 = (const float*)d_in[11];
    const float* We1  = (const float*)d_in[12];
    const float* be1  = (const float*)d_in[13];
    const float* W1_1 = (const float*)d_in[14];
    const float* b1_1 = (const float*)d_in[15];
    const float* g1   = (const float*)d_in[16];
    const float* bt1  = (const float*)d_in[17];
    const float* W2_1 = (const float*)d_in[18];
    const float* b2_1 = (const float*)d_in[19];
    const float* lin_w= (const float*)d_in[20];
    const float* lin_b= (const float*)d_in[21];

    float* ws = (float*)d_ws;
    float*  bufA  = ws;                       // h1 / h2      (6.4M floats)
    float*  bufB  = ws + 6400000;             // t1 / t2      (6.4M)
    float*  bufC  = ws + 12800000;            // x1           (6.4M)
    float2* csr   = (float2*)(ws + 19200000); // 800K float2
    int*    ibase = (int*)(ws + 20800000);
    int*    deg    = ibase;                   // 50000
    int*    rowptr = ibase + 50000;           // 50001
    int*    cursor = ibase + 100001;          // 50000
    int*    bsum   = ibase + 150001;          // 196
    float*  gsum   = ws + 20960000;           // 128
    float*  gsq    = gsum + 128;
    float*  scale  = gsq + 128;
    float*  shift  = scale + 128;
    float*  pooled = ws + 20960512;           // 512*128

    // ---- build CSR once
    hipMemsetAsync(deg, 0, N_NODES * sizeof(int), stream);
    hist_kernel<<<N_EDGES / 256, 256, 0, stream>>>(ei, deg);
    scan1_kernel<<<NB_SCAN, 256, 0, stream>>>(deg, rowptr, bsum);
    scan2_kernel<<<1, 256, 0, stream>>>(bsum);
    scan3_kernel<<<NB_SCAN, 256, 0, stream>>>(bsum, rowptr, cursor);
    scatter_kernel<<<N_EDGES / 256, 256, 0, stream>>>(ei, ew, cursor, csr);

    // ---- layer 1
    aggr_kernel<<<N_NODES / 4, 256, 0, stream>>>(x0, csr, rowptr, We0, be0, bufA);
    gemm_kernel<0><<<RT * 2, 256, 0, stream>>>(bufA, W1_0, b1_0, nullptr, nullptr, nullptr, bufB);
    hipMemsetAsync(gsum, 0, 256 * sizeof(float), stream);
    stats_kernel<<<256, 256, 0, stream>>>(bufB, gsum, gsq);
    bnfin_kernel<<<1, 128, 0, stream>>>(gsum, gsq, g0, bt0, scale, shift);
    gemm_kernel<1><<<RT * 2, 256, 0, stream>>>(bufB, W2_0, b2_0, scale, shift, nullptr, bufC);

    // ---- layer 2
    aggr_kernel<<<N_NODES / 4, 256, 0, stream>>>(bufC, csr, rowptr, We1, be1, bufA);
    gemm_kernel<0><<<RT * 2, 256, 0, stream>>>(bufA, W1_1, b1_1, nullptr, nullptr, nullptr, bufB);
    hipMemsetAsync(gsum, 0, 256 * sizeof(float), stream);
    stats_kernel<<<256, 256, 0, stream>>>(bufB, gsum, gsq);
    bnfin_kernel<<<1, 128, 0, stream>>>(gsum, gsq, g1, bt1, scale, shift);
    // fused: BN+ReLU -> GEMM -> ReLU -> segment-max pool (no dense x2 store)
    hipMemsetAsync(pooled, 0, (size_t)N_GRAPHS * C * sizeof(float), stream);
    gemm_kernel<2><<<RT * 2, 256, 0, stream>>>(bufB, W2_1, b2_1, scale, shift, batch, pooled);

    // ---- final linear
    final_kernel<<<N_GRAPHS, 64, 0, stream>>>(pooled, lin_w, lin_b, (float*)d_out);
}

// Round 8
// 496.685 us; speedup vs baseline: 1.2513x; 1.2513x over previous
//
#include <hip/hip_runtime.h>

#define N_NODES 50000
#define N_EDGES 800000
#define C 128
#define N_GRAPHS 512
#define OUTDIM 5
#define BN_EPS 1e-5f
#define NB_SCAN 196      // ceil(50000/256)
#define N_STRIPES 3125   // 50000/16 exact

typedef short bs8 __attribute__((ext_vector_type(8)));   // 8 bf16 (4 VGPR) MFMA operand
typedef float f32x4 __attribute__((ext_vector_type(4))); // MFMA accumulator

__device__ __forceinline__ unsigned short f2b(float f) {  // f32 -> bf16 RNE
    unsigned u = __float_as_uint(f);
    u += 0x7fffu + ((u >> 16) & 1u);
    return (unsigned short)(u >> 16);
}
__device__ __forceinline__ float b2f(unsigned v) {        // bf16 bits -> f32
    return __uint_as_float(v << 16);
}

// ================= f32 -> bf16 conversion (x0 and the four W matrices) =================
__global__ __launch_bounds__(256) void conv_kernel(const float* __restrict__ in,
                                                   unsigned short* __restrict__ out, int n4)
{
    int i = blockIdx.x * 256 + threadIdx.x;
    if (i < n4) {
        float4 v = reinterpret_cast<const float4*>(in)[i];
        ushort4 o;
        o.x = f2b(v.x); o.y = f2b(v.y); o.z = f2b(v.z); o.w = f2b(v.w);
        reinterpret_cast<ushort4*>(out)[i] = o;
    }
}

// ================= CSR build =================
__global__ __launch_bounds__(256) void hist_kernel(const int* __restrict__ ei,
                                                   int* __restrict__ deg)
{
    int e = blockIdx.x * 256 + threadIdx.x;
    atomicAdd(&deg[ei[N_EDGES + e]], 1);
}

__global__ __launch_bounds__(256) void scan1_kernel(const int* __restrict__ deg,
                                                    int* __restrict__ rowptr,
                                                    int* __restrict__ bsum)
{
    __shared__ int sh[256];
    int tid = threadIdx.x;
    int i = blockIdx.x * 256 + tid;
    int v = (i < N_NODES) ? deg[i] : 0;
    sh[tid] = v;
    __syncthreads();
    #pragma unroll
    for (int off = 1; off < 256; off <<= 1) {
        int t = (tid >= off) ? sh[tid - off] : 0;
        __syncthreads();
        sh[tid] += t;
        __syncthreads();
    }
    if (i < N_NODES) rowptr[i] = sh[tid] - v;
    if (tid == 255) bsum[blockIdx.x] = sh[255];
}

__global__ __launch_bounds__(256) void scan2_kernel(int* __restrict__ bsum)
{
    __shared__ int sh[256];
    int tid = threadIdx.x;
    int v = (tid < NB_SCAN) ? bsum[tid] : 0;
    sh[tid] = v;
    __syncthreads();
    #pragma unroll
    for (int off = 1; off < 256; off <<= 1) {
        int t = (tid >= off) ? sh[tid - off] : 0;
        __syncthreads();
        sh[tid] += t;
        __syncthreads();
    }
    if (tid < NB_SCAN) bsum[tid] = sh[tid] - v;
}

__global__ __launch_bounds__(256) void scan3_kernel(const int* __restrict__ bsum,
                                                    int* __restrict__ rowptr,
                                                    int* __restrict__ cursor)
{
    int i = blockIdx.x * 256 + threadIdx.x;
    if (i < N_NODES) {
        int v = rowptr[i] + bsum[blockIdx.x];
        rowptr[i] = v;
        cursor[i] = v;
    }
    if (i == 0) rowptr[N_NODES] = N_EDGES;
}

__global__ __launch_bounds__(256) void scatter_kernel(const int* __restrict__ ei,
                                                      const float* __restrict__ ew,
                                                      int* __restrict__ cursor,
                                                      float2* __restrict__ csr)
{
    int e = blockIdx.x * 256 + threadIdx.x;
    int dst = ei[N_EDGES + e];
    int pos = atomicAdd(&cursor[dst], 1);
    float2 ent;
    ent.x = __int_as_float(ei[e]);
    ent.y = ew[e];
    csr[pos] = ent;
}

// ================= atomic-free aggregation (bf16 features) =================
// one wave per node: h[node] = x[node] + sum_e relu(x[src_e] + w_e*We + be)
__global__ __launch_bounds__(256) void aggr_kernel(const unsigned short* __restrict__ x,
                                                   const float2* __restrict__ csr,
                                                   const int* __restrict__ rowptr,
                                                   const float* __restrict__ We,
                                                   const float* __restrict__ be,
                                                   unsigned short* __restrict__ hout)
{
    int node = blockIdx.x * 4 + (threadIdx.x >> 6);
    int lane = threadIdx.x & 63;
    int c = lane * 2;
    float2 wev = *reinterpret_cast<const float2*>(&We[c]);
    float2 bev = *reinterpret_cast<const float2*>(&be[c]);
    int p = rowptr[node], p1 = rowptr[node + 1];
    unsigned sv = *reinterpret_cast<const unsigned*>(&x[(size_t)node * C + c]);
    float ax = b2f(sv & 0xffffu), ay = b2f(sv >> 16);
    // 4-deep unroll: 4 outstanding gathers per wave for MLP
    for (; p + 4 <= p1; p += 4) {
        float2 e0 = csr[p], e1 = csr[p + 1], e2 = csr[p + 2], e3 = csr[p + 3];
        unsigned g0 = *reinterpret_cast<const unsigned*>(&x[(size_t)__float_as_int(e0.x) * C + c]);
        unsigned g1 = *reinterpret_cast<const unsigned*>(&x[(size_t)__float_as_int(e1.x) * C + c]);
        unsigned g2 = *reinterpret_cast<const unsigned*>(&x[(size_t)__float_as_int(e2.x) * C + c]);
        unsigned g3 = *reinterpret_cast<const unsigned*>(&x[(size_t)__float_as_int(e3.x) * C + c]);
        float m;
        m = b2f(g0 & 0xffffu) + e0.y * wev.x + bev.x; ax += fmaxf(m, 0.f);
        m = b2f(g0 >> 16)     + e0.y * wev.y + bev.y; ay += fmaxf(m, 0.f);
        m = b2f(g1 & 0xffffu) + e1.y * wev.x + bev.x; ax += fmaxf(m, 0.f);
        m = b2f(g1 >> 16)     + e1.y * wev.y + bev.y; ay += fmaxf(m, 0.f);
        m = b2f(g2 & 0xffffu) + e2.y * wev.x + bev.x; ax += fmaxf(m, 0.f);
        m = b2f(g2 >> 16)     + e2.y * wev.y + bev.y; ay += fmaxf(m, 0.f);
        m = b2f(g3 & 0xffffu) + e3.y * wev.x + bev.x; ax += fmaxf(m, 0.f);
        m = b2f(g3 >> 16)     + e3.y * wev.y + bev.y; ay += fmaxf(m, 0.f);
    }
    for (; p < p1; ++p) {
        float2 e0 = csr[p];
        unsigned g0 = *reinterpret_cast<const unsigned*>(&x[(size_t)__float_as_int(e0.x) * C + c]);
        float m;
        m = b2f(g0 & 0xffffu) + e0.y * wev.x + bev.x; ax += fmaxf(m, 0.f);
        m = b2f(g0 >> 16)     + e0.y * wev.y + bev.y; ay += fmaxf(m, 0.f);
    }
    unsigned o = (unsigned)f2b(ax) | ((unsigned)f2b(ay) << 16);
    *reinterpret_cast<unsigned*>(&hout[(size_t)node * C + c]) = o;
}

// ================= MFMA bf16 GEMM: 50000x128 @ (128x128)^T =================
// Per block: 4 waves; wave w owns cols [w*32, w*32+32) (two 16x16 col-tiles).
// W-frags hoisted in VGPRs; A-frags loaded straight from global (no LDS).
// A-frag layout: lane l: row = l&15, k = 8*(l>>4)+i (contiguous -> one 16B load)
// B operand = W[col][k] with col = l&15, same k pattern.
// D: col = l&15, row = 4*(l>>4)+r   [m89-verified]
// MODE 0: out = bf16(A@W.T + bias)
// MODE 1: a = relu(bf16(A)*scale+shift); out = bf16(relu(a@W.T + bias))
// MODE 2: like MODE 1 but atomicMax-pool f32 into pooled[batch[row]*C+col]
template<int MODE>
__global__ __launch_bounds__(256) void mgemm_kernel(
    const unsigned short* __restrict__ A,    // bf16 [M][128]
    const unsigned short* __restrict__ Wb,   // bf16 [128][128], [col][k]
    const float* __restrict__ bias,
    const float* __restrict__ scale,
    const float* __restrict__ shift,
    const int* __restrict__ batch,
    unsigned short* __restrict__ outb,       // MODE 0/1
    float* __restrict__ pooled)              // MODE 2
{
    const int wave = threadIdx.x >> 6;
    const int lane = threadIdx.x & 63;
    const int colbase = wave << 5;
    const int lr = lane & 15;
    const int lk = (lane >> 4) << 3;   // 0,8,16,24

    // hoist W fragments: 2 col-tiles x 4 k-chunks (32 VGPR)
    bs8 bf[2][4];
    #pragma unroll
    for (int ct = 0; ct < 2; ++ct)
        #pragma unroll
        for (int kc = 0; kc < 4; ++kc)
            bf[ct][kc] = *reinterpret_cast<const bs8*>(
                &Wb[(size_t)(colbase + ct * 16 + lr) * C + kc * 32 + lk]);

    const float bi0 = bias[colbase + lr];
    const float bi1 = bias[colbase + 16 + lr];

    float sc[4][8], sh[4][8];
    if (MODE >= 1) {
        #pragma unroll
        for (int kc = 0; kc < 4; ++kc)
            #pragma unroll
            for (int i = 0; i < 8; ++i) {
                sc[kc][i] = scale[kc * 32 + lk + i];
                sh[kc][i] = shift[kc * 32 + lk + i];
            }
    }

    for (int s = blockIdx.x; s < N_STRIPES; s += gridDim.x) {
        const int row0 = s << 4;
        bs8 af[4];
        #pragma unroll
        for (int kc = 0; kc < 4; ++kc) {
            bs8 raw = *reinterpret_cast<const bs8*>(
                &A[(size_t)(row0 + lr) * C + kc * 32 + lk]);
            if (MODE == 0) {
                af[kc] = raw;
            } else {
                union { bs8 v; unsigned short u[8]; } pk;
                #pragma unroll
                for (int i = 0; i < 8; ++i) {
                    float f = b2f((unsigned)(unsigned short)raw[i]);
                    pk.u[i] = f2b(fmaxf(f * sc[kc][i] + sh[kc][i], 0.f));
                }
                af[kc] = pk.v;
            }
        }

        f32x4 a0 = {0.f, 0.f, 0.f, 0.f};
        f32x4 a1 = {0.f, 0.f, 0.f, 0.f};
        #pragma unroll
        for (int kc = 0; kc < 4; ++kc) {
            a0 = __builtin_amdgcn_mfma_f32_16x16x32_bf16(af[kc], bf[0][kc], a0, 0, 0, 0);
            a1 = __builtin_amdgcn_mfma_f32_16x16x32_bf16(af[kc], bf[1][kc], a1, 0, 0, 0);
        }

        const int orow = row0 + ((lane >> 4) << 2);
        if (MODE == 2) {
            #pragma unroll
            for (int r = 0; r < 4; ++r) {
                int g = batch[orow + r];
                float o0 = fmaxf(a0[r] + bi0, 0.f);
                float o1 = fmaxf(a1[r] + bi1, 0.f);
                atomicMax(reinterpret_cast<int*>(&pooled[(size_t)g * C + colbase + lr]),
                          __float_as_int(o0));
                atomicMax(reinterpret_cast<int*>(&pooled[(size_t)g * C + colbase + 16 + lr]),
                          __float_as_int(o1));
            }
        } else {
            #pragma unroll
            for (int r = 0; r < 4; ++r) {
                float o0 = a0[r] + bi0;
                float o1 = a1[r] + bi1;
                if (MODE == 1) { o0 = fmaxf(o0, 0.f); o1 = fmaxf(o1, 0.f); }
                outb[(size_t)(orow + r) * C + colbase + lr]      = f2b(o0);
                outb[(size_t)(orow + r) * C + colbase + 16 + lr] = f2b(o1);
            }
        }
    }
}

// ================= BatchNorm stats (bf16 input) =================
__global__ __launch_bounds__(256) void stats_kernel(const unsigned short* __restrict__ t,
                                                    float* __restrict__ gsum, float* __restrict__ gsq)
{
    int tid = threadIdx.x;
    int c = tid & 127;
    int half = tid >> 7;
    float s = 0.f, q = 0.f;
    for (int n = blockIdx.x * 2 + half; n < N_NODES; n += gridDim.x * 2) {
        float v = b2f((unsigned)t[(size_t)n * C + c]);
        s += v; q += v * v;
    }
    __shared__ float ls[256];
    ls[tid] = s; __syncthreads();
    if (tid < 128) unsafeAtomicAdd(&gsum[tid], ls[tid] + ls[tid + 128]);
    __syncthreads();
    ls[tid] = q; __syncthreads();
    if (tid < 128) unsafeAtomicAdd(&gsq[tid], ls[tid] + ls[tid + 128]);
}

__global__ void bnfin_kernel(const float* __restrict__ gsum, const float* __restrict__ gsq,
                             const float* __restrict__ g, const float* __restrict__ bt,
                             float* __restrict__ scale, float* __restrict__ shift)
{
    int c = threadIdx.x;
    float mu  = gsum[c] * (1.f / N_NODES);
    float var = gsq[c] * (1.f / N_NODES) - mu * mu;
    float rs  = rsqrtf(var + BN_EPS);
    float s   = rs * g[c];
    scale[c] = s;
    shift[c] = bt[c] - mu * s;
}

// ================= final linear (f32 pooled) =================
__global__ __launch_bounds__(64) void final_kernel(const float* __restrict__ pooled,
                                                   const float* __restrict__ lw,
                                                   const float* __restrict__ lb,
                                                   float* __restrict__ out)
{
    int gph = blockIdx.x;
    int lane = threadIdx.x;
    float v0 = pooled[(size_t)gph * C + lane];
    float v1 = pooled[(size_t)gph * C + lane + 64];
    for (int o = 0; o < OUTDIM; ++o) {
        float p = v0 * lw[o * C + lane] + v1 * lw[o * C + lane + 64];
        #pragma unroll
        for (int off = 32; off > 0; off >>= 1) p += __shfl_down(p, off);
        if (lane == 0) out[gph * OUTDIM + o] = p + lb[o];
    }
}

extern "C" void kernel_launch(void* const* d_in, const int* in_sizes, int n_in,
                              void* d_out, int out_size, void* d_ws, size_t ws_size,
                              hipStream_t stream)
{
    const float* x0   = (const float*)d_in[0];
    const int*   ei   = (const int*)  d_in[1];
    const float* ew   = (const float*)d_in[2];
    const int*   batch= (const int*)  d_in[3];
    const float* We0  = (const float*)d_in[4];
    const float* be0  = (const float*)d_in[5];
    const float* W1_0 = (const float*)d_in[6];
    const float* b1_0 = (const float*)d_in[7];
    const float* g0   = (const float*)d_in[8];
    const float* bt0  = (const float*)d_in[9];
    const float* W2_0 = (const float*)d_in[10];
    const float* b2_0 = (const float*)d_in[11];
    const float* We1  = (const float*)d_in[12];
    const float* be1  = (const float*)d_in[13];
    const float* W1_1 = (const float*)d_in[14];
    const float* b1_1 = (const float*)d_in[15];
    const float* g1   = (const float*)d_in[16];
    const float* bt1  = (const float*)d_in[17];
    const float* W2_1 = (const float*)d_in[18];
    const float* b2_1 = (const float*)d_in[19];
    const float* lin_w= (const float*)d_in[20];
    const float* lin_b= (const float*)d_in[21];

    char* base = (char*)d_ws;
    unsigned short* xb = (unsigned short*)(base);              // 12.8 MB  bf16 x0
    unsigned short* hA = (unsigned short*)(base + 12800000);   // 12.8 MB  h
    unsigned short* tB = (unsigned short*)(base + 25600000);   // 12.8 MB  t
    unsigned short* xC = (unsigned short*)(base + 38400000);   // 12.8 MB  x1
    unsigned short* Wb = (unsigned short*)(base + 51200000);   // 4 x 32 KB bf16 W
    float2* csr   = (float2*)(base + 51400000);                // 6.4 MB
    int*    deg    = (int*)(base + 57800000);                  // 200 KB
    int*    rowptr = (int*)(base + 58000000);                  // 200 KB
    int*    cursor = (int*)(base + 58200008);                  // 200 KB
    int*    bsum   = (int*)(base + 58400008);                  // ~1 KB
    float*  gsum   = (float*)(base + 58401024);
    float*  gsq    = gsum + 128;
    float*  scale  = gsq + 128;
    float*  shift  = scale + 128;
    float*  pooled = (float*)(base + 58403072);                // 256 KB

    // ---- convert x0 and the 4 weight matrices to bf16
    conv_kernel<<<6250, 256, 0, stream>>>(x0, xb, N_NODES * C / 4);
    conv_kernel<<<16, 256, 0, stream>>>(W1_0, Wb + 0 * 16384, 4096);
    conv_kernel<<<16, 256, 0, stream>>>(W2_0, Wb + 1 * 16384, 4096);
    conv_kernel<<<16, 256, 0, stream>>>(W1_1, Wb + 2 * 16384, 4096);
    conv_kernel<<<16, 256, 0, stream>>>(W2_1, Wb + 3 * 16384, 4096);

    // ---- build CSR once
    hipMemsetAsync(deg, 0, N_NODES * sizeof(int), stream);
    hist_kernel<<<N_EDGES / 256, 256, 0, stream>>>(ei, deg);
    scan1_kernel<<<NB_SCAN, 256, 0, stream>>>(deg, rowptr, bsum);
    scan2_kernel<<<1, 256, 0, stream>>>(bsum);
    scan3_kernel<<<NB_SCAN, 256, 0, stream>>>(bsum, rowptr, cursor);
    scatter_kernel<<<N_EDGES / 256, 256, 0, stream>>>(ei, ew, cursor, csr);

    // ---- layer 1
    aggr_kernel<<<N_NODES / 4, 256, 0, stream>>>(xb, csr, rowptr, We0, be0, hA);
    mgemm_kernel<0><<<768, 256, 0, stream>>>(hA, Wb + 0 * 16384, b1_0,
                                             nullptr, nullptr, nullptr, tB, nullptr);
    hipMemsetAsync(gsum, 0, 256 * sizeof(float), stream);
    stats_kernel<<<256, 256, 0, stream>>>(tB, gsum, gsq);
    bnfin_kernel<<<1, 128, 0, stream>>>(gsum, gsq, g0, bt0, scale, shift);
    mgemm_kernel<1><<<768, 256, 0, stream>>>(tB, Wb + 1 * 16384, b2_0,
                                             scale, shift, nullptr, xC, nullptr);

    // ---- layer 2
    aggr_kernel<<<N_NODES / 4, 256, 0, stream>>>(xC, csr, rowptr, We1, be1, hA);
    mgemm_kernel<0><<<768, 256, 0, stream>>>(hA, Wb + 2 * 16384, b1_1,
                                             nullptr, nullptr, nullptr, tB, nullptr);
    hipMemsetAsync(gsum, 0, 256 * sizeof(float), stream);
    stats_kernel<<<256, 256, 0, stream>>>(tB, gsum, gsq);
    bnfin_kernel<<<1, 128, 0, stream>>>(gsum, gsq, g1, bt1, scale, shift);
    hipMemsetAsync(pooled, 0, (size_t)N_GRAPHS * C * sizeof(float), stream);
    // fused: BN+ReLU -> GEMM -> ReLU -> segment-max pool
    mgemm_kernel<2><<<768, 256, 0, stream>>>(tB, Wb + 3 * 16384, b2_1,
                                             scale, shift, batch, nullptr, pooled);

    // ---- final linear
    final_kernel<<<N_GRAPHS, 64, 0, stream>>>(pooled, lin_w, lin_b, (float*)d_out);
}

// Round 11
// 423.739 us; speedup vs baseline: 1.4667x; 1.1721x over previous
//
#include <hip/hip_runtime.h>

#define N_NODES 50000
#define N_EDGES 800000
#define C 128
#define N_GRAPHS 512
#define OUTDIM 5
#define BN_EPS 1e-5f
#define NB_SCAN 196      // ceil(50000/256)
#define N_STRIPES 3125   // 50000/16 exact

typedef short bs8 __attribute__((ext_vector_type(8)));   // 8 bf16 (4 VGPR) MFMA operand
typedef float f32x4 __attribute__((ext_vector_type(4))); // MFMA accumulator
typedef unsigned short us8 __attribute__((ext_vector_type(8)));

__device__ __forceinline__ unsigned short f2b(float f) {  // f32 -> bf16 RNE
    unsigned u = __float_as_uint(f);
    u += 0x7fffu + ((u >> 16) & 1u);
    return (unsigned short)(u >> 16);
}
__device__ __forceinline__ float b2f(unsigned v) {        // bf16 bits -> f32
    return __uint_as_float(v << 16);
}

// ================= f32 -> bf16 conversion =================
__global__ __launch_bounds__(256) void conv_kernel(const float* __restrict__ in,
                                                   unsigned short* __restrict__ out, int n4)
{
    int i = blockIdx.x * 256 + threadIdx.x;
    if (i < n4) {
        float4 v = reinterpret_cast<const float4*>(in)[i];
        ushort4 o;
        o.x = f2b(v.x); o.y = f2b(v.y); o.z = f2b(v.z); o.w = f2b(v.w);
        reinterpret_cast<ushort4*>(out)[i] = o;
    }
}

// ================= CSR build =================
__global__ __launch_bounds__(256) void hist_kernel(const int* __restrict__ ei,
                                                   int* __restrict__ deg)
{
    int e = blockIdx.x * 256 + threadIdx.x;
    atomicAdd(&deg[ei[N_EDGES + e]], 1);
}

__global__ __launch_bounds__(256) void scan1_kernel(const int* __restrict__ deg,
                                                    int* __restrict__ rowptr,
                                                    int* __restrict__ bsum)
{
    __shared__ int sh[256];
    int tid = threadIdx.x;
    int i = blockIdx.x * 256 + tid;
    int v = (i < N_NODES) ? deg[i] : 0;
    sh[tid] = v;
    __syncthreads();
    #pragma unroll
    for (int off = 1; off < 256; off <<= 1) {
        int t = (tid >= off) ? sh[tid - off] : 0;
        __syncthreads();
        sh[tid] += t;
        __syncthreads();
    }
    if (i < N_NODES) rowptr[i] = sh[tid] - v;
    if (tid == 255) bsum[blockIdx.x] = sh[255];
}

__global__ __launch_bounds__(256) void scan2_kernel(int* __restrict__ bsum)
{
    __shared__ int sh[256];
    int tid = threadIdx.x;
    int v = (tid < NB_SCAN) ? bsum[tid] : 0;
    sh[tid] = v;
    __syncthreads();
    #pragma unroll
    for (int off = 1; off < 256; off <<= 1) {
        int t = (tid >= off) ? sh[tid - off] : 0;
        __syncthreads();
        sh[tid] += t;
        __syncthreads();
    }
    if (tid < NB_SCAN) bsum[tid] = sh[tid] - v;
}

__global__ __launch_bounds__(256) void scan3_kernel(const int* __restrict__ bsum,
                                                    int* __restrict__ rowptr,
                                                    int* __restrict__ cursor)
{
    int i = blockIdx.x * 256 + threadIdx.x;
    if (i < N_NODES) {
        int v = rowptr[i] + bsum[blockIdx.x];
        rowptr[i] = v;
        cursor[i] = v;
    }
    if (i == 0) rowptr[N_NODES] = N_EDGES;
}

__global__ __launch_bounds__(256) void scatter_kernel(const int* __restrict__ ei,
                                                      const float* __restrict__ ew,
                                                      int* __restrict__ cursor,
                                                      float2* __restrict__ csr)
{
    int e = blockIdx.x * 256 + threadIdx.x;
    int dst = ei[N_EDGES + e];
    int pos = atomicAdd(&cursor[dst], 1);
    float2 ent;
    ent.x = __int_as_float(ei[e]);
    ent.y = ew[e];
    csr[pos] = ent;
}

// ================= atomic-free aggregation (bf16 features) =================
__global__ __launch_bounds__(256) void aggr_kernel(const unsigned short* __restrict__ x,
                                                   const float2* __restrict__ csr,
                                                   const int* __restrict__ rowptr,
                                                   const float* __restrict__ We,
                                                   const float* __restrict__ be,
                                                   unsigned short* __restrict__ hout)
{
    int node = blockIdx.x * 4 + (threadIdx.x >> 6);
    int lane = threadIdx.x & 63;
    int c = lane * 2;
    float2 wev = *reinterpret_cast<const float2*>(&We[c]);
    float2 bev = *reinterpret_cast<const float2*>(&be[c]);
    int p = rowptr[node], p1 = rowptr[node + 1];
    unsigned sv = *reinterpret_cast<const unsigned*>(&x[(size_t)node * C + c]);
    float ax = b2f(sv & 0xffffu), ay = b2f(sv >> 16);
    for (; p + 4 <= p1; p += 4) {
        float2 e0 = csr[p], e1 = csr[p + 1], e2 = csr[p + 2], e3 = csr[p + 3];
        unsigned g0 = *reinterpret_cast<const unsigned*>(&x[(size_t)__float_as_int(e0.x) * C + c]);
        unsigned g1 = *reinterpret_cast<const unsigned*>(&x[(size_t)__float_as_int(e1.x) * C + c]);
        unsigned g2 = *reinterpret_cast<const unsigned*>(&x[(size_t)__float_as_int(e2.x) * C + c]);
        unsigned g3 = *reinterpret_cast<const unsigned*>(&x[(size_t)__float_as_int(e3.x) * C + c]);
        float m;
        m = b2f(g0 & 0xffffu) + e0.y * wev.x + bev.x; ax += fmaxf(m, 0.f);
        m = b2f(g0 >> 16)     + e0.y * wev.y + bev.y; ay += fmaxf(m, 0.f);
        m = b2f(g1 & 0xffffu) + e1.y * wev.x + bev.x; ax += fmaxf(m, 0.f);
        m = b2f(g1 >> 16)     + e1.y * wev.y + bev.y; ay += fmaxf(m, 0.f);
        m = b2f(g2 & 0xffffu) + e2.y * wev.x + bev.x; ax += fmaxf(m, 0.f);
        m = b2f(g2 >> 16)     + e2.y * wev.y + bev.y; ay += fmaxf(m, 0.f);
        m = b2f(g3 & 0xffffu) + e3.y * wev.x + bev.x; ax += fmaxf(m, 0.f);
        m = b2f(g3 >> 16)     + e3.y * wev.y + bev.y; ay += fmaxf(m, 0.f);
    }
    for (; p < p1; ++p) {
        float2 e0 = csr[p];
        unsigned g0 = *reinterpret_cast<const unsigned*>(&x[(size_t)__float_as_int(e0.x) * C + c]);
        float m;
        m = b2f(g0 & 0xffffu) + e0.y * wev.x + bev.x; ax += fmaxf(m, 0.f);
        m = b2f(g0 >> 16)     + e0.y * wev.y + bev.y; ay += fmaxf(m, 0.f);
    }
    unsigned o = (unsigned)f2b(ax) | ((unsigned)f2b(ay) << 16);
    *reinterpret_cast<unsigned*>(&hout[(size_t)node * C + c]) = o;
}

// ================= MFMA bf16 GEMM with prefetch + sector-aligned epilogue =================
// Per block: 4 waves; wave w owns cols [w*32, w*32+32).
// A-frags prefetched one stripe ahead (no barriers in loop -> loads stay in flight).
// Epilogue: wave-private LDS transpose -> one ushort8 (16B) store per lane,
// 16 rows x 64B full sectors per wave (fixes the 3.4x write amplification of
// the 2-byte scalar-store epilogue, R8 counters).
// MODE 0: out = bf16(A@W.T + bias)
// MODE 1: a = relu(bf16(A)*scale+shift); out = bf16(relu(a@W.T + bias))
// MODE 2: like MODE 1 but atomicMax-pool f32 into pooled[batch[row]*C+col]
//         (4 rows merged in-register when same graph: batch is sorted)
template<int MODE>
__global__ __launch_bounds__(256) void mgemm_kernel(
    const unsigned short* __restrict__ A,
    const unsigned short* __restrict__ Wb,
    const float* __restrict__ bias,
    const float* __restrict__ scale,
    const float* __restrict__ shift,
    const int* __restrict__ batch,
    unsigned short* __restrict__ outb,
    float* __restrict__ pooled)
{
    __shared__ __align__(16) unsigned short xpose[4][16][40];  // per-wave [16 rows][32+pad]
    const int wave = threadIdx.x >> 6;
    const int lane = threadIdx.x & 63;
    const int colbase = wave << 5;
    const int lr = lane & 15;
    const int lk = (lane >> 4) << 3;   // 0,8,16,24

    // hoist W fragments: 2 col-tiles x 4 k-chunks (32 VGPR)
    bs8 bf[2][4];
    #pragma unroll
    for (int ct = 0; ct < 2; ++ct)
        #pragma unroll
        for (int kc = 0; kc < 4; ++kc)
            bf[ct][kc] = *reinterpret_cast<const bs8*>(
                &Wb[(size_t)(colbase + ct * 16 + lr) * C + kc * 32 + lk]);

    const float bi0 = bias[colbase + lr];
    const float bi1 = bias[colbase + 16 + lr];

    float sc[4][8], sh[4][8];
    if (MODE >= 1) {
        #pragma unroll
        for (int kc = 0; kc < 4; ++kc)
            #pragma unroll
            for (int i = 0; i < 8; ++i) {
                sc[kc][i] = scale[kc * 32 + lk + i];
                sh[kc][i] = shift[kc * 32 + lk + i];
            }
    }

    int s = blockIdx.x;
    bs8 raw[4];
    #pragma unroll
    for (int kc = 0; kc < 4; ++kc)
        raw[kc] = *reinterpret_cast<const bs8*>(
            &A[(size_t)(s * 16 + lr) * C + kc * 32 + lk]);

    while (true) {
        const int snext = s + gridDim.x;
        bs8 rawn[4];
        if (snext < N_STRIPES) {
            #pragma unroll
            for (int kc = 0; kc < 4; ++kc)
                rawn[kc] = *reinterpret_cast<const bs8*>(
                    &A[(size_t)(snext * 16 + lr) * C + kc * 32 + lk]);
        }

        bs8 af[4];
        #pragma unroll
        for (int kc = 0; kc < 4; ++kc) {
            if (MODE == 0) {
                af[kc] = raw[kc];
            } else {
                union { bs8 v; unsigned short u[8]; } pk;
                #pragma unroll
                for (int i = 0; i < 8; ++i) {
                    float f = b2f((unsigned)(unsigned short)raw[kc][i]);
                    pk.u[i] = f2b(fmaxf(f * sc[kc][i] + sh[kc][i], 0.f));
                }
                af[kc] = pk.v;
            }
        }

        f32x4 a0 = {0.f, 0.f, 0.f, 0.f};
        f32x4 a1 = {0.f, 0.f, 0.f, 0.f};
        #pragma unroll
        for (int kc = 0; kc < 4; ++kc) {
            a0 = __builtin_amdgcn_mfma_f32_16x16x32_bf16(af[kc], bf[0][kc], a0, 0, 0, 0);
            a1 = __builtin_amdgcn_mfma_f32_16x16x32_bf16(af[kc], bf[1][kc], a1, 0, 0, 0);
        }

        const int row0 = s << 4;
        if (MODE == 2) {
            const int orow = row0 + ((lane >> 4) << 2);
            float o0[4], o1[4];
            #pragma unroll
            for (int r = 0; r < 4; ++r) {
                o0[r] = fmaxf(a0[r] + bi0, 0.f);
                o1[r] = fmaxf(a1[r] + bi1, 0.f);
            }
            int gA = batch[orow], gB = batch[orow + 3];
            if (gA == gB) {   // common case: 4 rows same graph (sorted batch, ~98 nodes/graph)
                float m0 = fmaxf(fmaxf(o0[0], o0[1]), fmaxf(o0[2], o0[3]));
                float m1 = fmaxf(fmaxf(o1[0], o1[1]), fmaxf(o1[2], o1[3]));
                atomicMax(reinterpret_cast<int*>(&pooled[(size_t)gA * C + colbase + lr]),
                          __float_as_int(m0));
                atomicMax(reinterpret_cast<int*>(&pooled[(size_t)gA * C + colbase + 16 + lr]),
                          __float_as_int(m1));
            } else {
                #pragma unroll
                for (int r = 0; r < 4; ++r) {
                    int g = batch[orow + r];
                    atomicMax(reinterpret_cast<int*>(&pooled[(size_t)g * C + colbase + lr]),
                              __float_as_int(o0[r]));
                    atomicMax(reinterpret_cast<int*>(&pooled[(size_t)g * C + colbase + 16 + lr]),
                              __float_as_int(o1[r]));
                }
            }
        } else {
            // wave-private LDS transpose: frag layout -> row-contiguous 16B/lane
            #pragma unroll
            for (int r = 0; r < 4; ++r) {
                int rl = ((lane >> 4) << 2) + r;
                float o0 = a0[r] + bi0;
                float o1 = a1[r] + bi1;
                if (MODE == 1) { o0 = fmaxf(o0, 0.f); o1 = fmaxf(o1, 0.f); }
                xpose[wave][rl][lr]      = f2b(o0);
                xpose[wave][rl][lr + 16] = f2b(o1);
            }
            __builtin_amdgcn_sched_barrier(0);   // pin ds_write -> ds_read order (same wave, in-order DS)
            us8 v = *reinterpret_cast<const us8*>(&xpose[wave][lane >> 2][(lane & 3) * 8]);
            *reinterpret_cast<us8*>(
                &outb[(size_t)(row0 + (lane >> 2)) * C + colbase + (lane & 3) * 8]) = v;
            __builtin_amdgcn_sched_barrier(0);   // keep next iter's ds_writes after this read
        }

        if (snext >= N_STRIPES) break;
        #pragma unroll
        for (int kc = 0; kc < 4; ++kc) raw[kc] = rawn[kc];
        s = snext;
    }
}

// ================= BatchNorm stats (bf16 input) =================
__global__ __launch_bounds__(256) void stats_kernel(const unsigned short* __restrict__ t,
                                                    float* __restrict__ gsum, float* __restrict__ gsq)
{
    int tid = threadIdx.x;
    int c = tid & 127;
    int half = tid >> 7;
    float s = 0.f, q = 0.f;
    for (int n = blockIdx.x * 2 + half; n < N_NODES; n += gridDim.x * 2) {
        float v = b2f((unsigned)t[(size_t)n * C + c]);
        s += v; q += v * v;
    }
    __shared__ float ls[256];
    ls[tid] = s; __syncthreads();
    if (tid < 128) unsafeAtomicAdd(&gsum[tid], ls[tid] + ls[tid + 128]);
    __syncthreads();
    ls[tid] = q; __syncthreads();
    if (tid < 128) unsafeAtomicAdd(&gsq[tid], ls[tid] + ls[tid + 128]);
}

__global__ void bnfin_kernel(const float* __restrict__ gsum, const float* __restrict__ gsq,
                             const float* __restrict__ g, const float* __restrict__ bt,
                             float* __restrict__ scale, float* __restrict__ shift)
{
    int c = threadIdx.x;
    float mu  = gsum[c] * (1.f / N_NODES);
    float var = gsq[c] * (1.f / N_NODES) - mu * mu;
    float rs  = rsqrtf(var + BN_EPS);
    float s   = rs * g[c];
    scale[c] = s;
    shift[c] = bt[c] - mu * s;
}

// ================= final linear (f32 pooled) =================
__global__ __launch_bounds__(64) void final_kernel(const float* __restrict__ pooled,
                                                   const float* __restrict__ lw,
                                                   const float* __restrict__ lb,
                                                   float* __restrict__ out)
{
    int gph = blockIdx.x;
    int lane = threadIdx.x;
    float v0 = pooled[(size_t)gph * C + lane];
    float v1 = pooled[(size_t)gph * C + lane + 64];
    for (int o = 0; o < OUTDIM; ++o) {
        float p = v0 * lw[o * C + lane] + v1 * lw[o * C + lane + 64];
        #pragma unroll
        for (int off = 32; off > 0; off >>= 1) p += __shfl_down(p, off);
        if (lane == 0) out[gph * OUTDIM + o] = p + lb[o];
    }
}

extern "C" void kernel_launch(void* const* d_in, const int* in_sizes, int n_in,
                              void* d_out, int out_size, void* d_ws, size_t ws_size,
                              hipStream_t stream)
{
    const float* x0   = (const float*)d_in[0];
    const int*   ei   = (const int*)  d_in[1];
    const float* ew   = (const float*)d_in[2];
    const int*   batch= (const int*)  d_in[3];
    const float* We0  = (const float*)d_in[4];
    const float* be0  = (const float*)d_in[5];
    const float* W1_0 = (const float*)d_in[6];
    const float* b1_0 = (const float*)d_in[7];
    const float* g0   = (const float*)d_in[8];
    const float* bt0  = (const float*)d_in[9];
    const float* W2_0 = (const float*)d_in[10];
    const float* b2_0 = (const float*)d_in[11];
    const float* We1  = (const float*)d_in[12];
    const float* be1  = (const float*)d_in[13];
    const float* W1_1 = (const float*)d_in[14];
    const float* b1_1 = (const float*)d_in[15];
    const float* g1   = (const float*)d_in[16];
    const float* bt1  = (const float*)d_in[17];
    const float* W2_1 = (const float*)d_in[18];
    const float* b2_1 = (const float*)d_in[19];
    const float* lin_w= (const float*)d_in[20];
    const float* lin_b= (const float*)d_in[21];

    char* base = (char*)d_ws;
    unsigned short* xb = (unsigned short*)(base);              // 12.8 MB  bf16 x0
    unsigned short* hA = (unsigned short*)(base + 12800000);   // 12.8 MB  h
    unsigned short* tB = (unsigned short*)(base + 25600000);   // 12.8 MB  t
    unsigned short* xC = (unsigned short*)(base + 38400000);   // 12.8 MB  x1
    unsigned short* Wb = (unsigned short*)(base + 51200000);   // 4 x 32 KB bf16 W
    float2* csr   = (float2*)(base + 51400000);                // 6.4 MB
    int*    deg    = (int*)(base + 57800000);                  // 200 KB
    int*    rowptr = (int*)(base + 58000000);                  // 200 KB
    int*    cursor = (int*)(base + 58200008);                  // 200 KB
    int*    bsum   = (int*)(base + 58400008);                  // ~1 KB
    float*  gsum   = (float*)(base + 58401024);
    float*  gsq    = gsum + 128;
    float*  scale  = gsq + 128;
    float*  shift  = scale + 128;
    float*  pooled = (float*)(base + 58403072);                // 256 KB

    // ---- convert x0 and the 4 weight matrices to bf16
    conv_kernel<<<6250, 256, 0, stream>>>(x0, xb, N_NODES * C / 4);
    conv_kernel<<<16, 256, 0, stream>>>(W1_0, Wb + 0 * 16384, 4096);
    conv_kernel<<<16, 256, 0, stream>>>(W2_0, Wb + 1 * 16384, 4096);
    conv_kernel<<<16, 256, 0, stream>>>(W1_1, Wb + 2 * 16384, 4096);
    conv_kernel<<<16, 256, 0, stream>>>(W2_1, Wb + 3 * 16384, 4096);

    // ---- build CSR once
    hipMemsetAsync(deg, 0, N_NODES * sizeof(int), stream);
    hist_kernel<<<N_EDGES / 256, 256, 0, stream>>>(ei, deg);
    scan1_kernel<<<NB_SCAN, 256, 0, stream>>>(deg, rowptr, bsum);
    scan2_kernel<<<1, 256, 0, stream>>>(bsum);
    scan3_kernel<<<NB_SCAN, 256, 0, stream>>>(bsum, rowptr, cursor);
    scatter_kernel<<<N_EDGES / 256, 256, 0, stream>>>(ei, ew, cursor, csr);

    // ---- layer 1
    aggr_kernel<<<N_NODES / 4, 256, 0, stream>>>(xb, csr, rowptr, We0, be0, hA);
    mgemm_kernel<0><<<768, 256, 0, stream>>>(hA, Wb + 0 * 16384, b1_0,
                                             nullptr, nullptr, nullptr, tB, nullptr);
    hipMemsetAsync(gsum, 0, 256 * sizeof(float), stream);
    stats_kernel<<<256, 256, 0, stream>>>(tB, gsum, gsq);
    bnfin_kernel<<<1, 128, 0, stream>>>(gsum, gsq, g0, bt0, scale, shift);
    mgemm_kernel<1><<<768, 256, 0, stream>>>(tB, Wb + 1 * 16384, b2_0,
                                             scale, shift, nullptr, xC, nullptr);

    // ---- layer 2
    aggr_kernel<<<N_NODES / 4, 256, 0, stream>>>(xC, csr, rowptr, We1, be1, hA);
    mgemm_kernel<0><<<768, 256, 0, stream>>>(hA, Wb + 2 * 16384, b1_1,
                                             nullptr, nullptr, nullptr, tB, nullptr);
    hipMemsetAsync(gsum, 0, 256 * sizeof(float), stream);
    stats_kernel<<<256, 256, 0, stream>>>(tB, gsum, gsq);
    bnfin_kernel<<<1, 128, 0, stream>>>(gsum, gsq, g1, bt1, scale, shift);
    hipMemsetAsync(pooled, 0, (size_t)N_GRAPHS * C * sizeof(float), stream);
    mgemm_kernel<2><<<768, 256, 0, stream>>>(tB, Wb + 3 * 16384, b2_1,
                                             scale, shift, batch, nullptr, pooled);

    // ---- final linear
    final_kernel<<<N_GRAPHS, 64, 0, stream>>>(pooled, lin_w, lin_b, (float*)d_out);
}

// Round 12
// 398.410 us; speedup vs baseline: 1.5600x; 1.0636x over previous
//
#include <hip/hip_runtime.h>

#define N_NODES 50000
#define N_EDGES 800000
#define C 128
#define N_GRAPHS 512
#define OUTDIM 5
#define BN_EPS 1e-5f
#define NB_SCAN 196      // ceil(50000/256)
#define N_STRIPES 3125   // 50000/16 exact

typedef short bs8 __attribute__((ext_vector_type(8)));   // 8 bf16 (4 VGPR) MFMA operand
typedef float f32x4 __attribute__((ext_vector_type(4))); // MFMA accumulator
typedef unsigned short us8 __attribute__((ext_vector_type(8)));

__device__ __forceinline__ unsigned short f2b(float f) {  // f32 -> bf16 RNE
    unsigned u = __float_as_uint(f);
    u += 0x7fffu + ((u >> 16) & 1u);
    return (unsigned short)(u >> 16);
}
__device__ __forceinline__ float b2f(unsigned v) {        // bf16 bits -> f32
    return __uint_as_float(v << 16);
}
__device__ __forceinline__ unsigned short f2h(float f) {  // f32 -> fp16 bits
    union { _Float16 h; unsigned short s; } cv;
    cv.h = (_Float16)f;
    return cv.s;
}
__device__ __forceinline__ float h2f(unsigned short s) {  // fp16 bits -> f32
    union { unsigned short s; _Float16 h; } cv;
    cv.s = s;
    return (float)cv.h;
}

// ================= f32 -> bf16 conversion (x0) =================
__global__ __launch_bounds__(256) void conv_kernel(const float* __restrict__ in,
                                                   unsigned short* __restrict__ out, int n4)
{
    int i = blockIdx.x * 256 + threadIdx.x;
    if (i < n4) {
        float4 v = reinterpret_cast<const float4*>(in)[i];
        ushort4 o;
        o.x = f2b(v.x); o.y = f2b(v.y); o.z = f2b(v.z); o.w = f2b(v.w);
        reinterpret_cast<ushort4*>(out)[i] = o;
    }
}

// all four 128x128 weight matrices in one launch (64 blocks; 16 per matrix)
__global__ __launch_bounds__(256) void convw_kernel(const float* __restrict__ w0,
                                                    const float* __restrict__ w1,
                                                    const float* __restrict__ w2,
                                                    const float* __restrict__ w3,
                                                    unsigned short* __restrict__ out)
{
    const float* src[4] = {w0, w1, w2, w3};
    int m = blockIdx.x >> 4;
    int i = (blockIdx.x & 15) * 256 + threadIdx.x;   // 0..4095 float4
    float4 v = reinterpret_cast<const float4*>(src[m])[i];
    ushort4 o;
    o.x = f2b(v.x); o.y = f2b(v.y); o.z = f2b(v.z); o.w = f2b(v.w);
    reinterpret_cast<ushort4*>(out + m * 16384)[i] = o;
}

// ================= CSR build =================
__global__ __launch_bounds__(256) void hist_kernel(const int* __restrict__ ei,
                                                   int* __restrict__ deg)
{
    int e = blockIdx.x * 256 + threadIdx.x;
    atomicAdd(&deg[ei[N_EDGES + e]], 1);
}

__global__ __launch_bounds__(256) void scan1_kernel(const int* __restrict__ deg,
                                                    int* __restrict__ rowptr,
                                                    int* __restrict__ bsum)
{
    __shared__ int sh[256];
    int tid = threadIdx.x;
    int i = blockIdx.x * 256 + tid;
    int v = (i < N_NODES) ? deg[i] : 0;
    sh[tid] = v;
    __syncthreads();
    #pragma unroll
    for (int off = 1; off < 256; off <<= 1) {
        int t = (tid >= off) ? sh[tid - off] : 0;
        __syncthreads();
        sh[tid] += t;
        __syncthreads();
    }
    if (i < N_NODES) rowptr[i] = sh[tid] - v;
    if (tid == 255) bsum[blockIdx.x] = sh[255];
}

__global__ __launch_bounds__(256) void scan2_kernel(int* __restrict__ bsum)
{
    __shared__ int sh[256];
    int tid = threadIdx.x;
    int v = (tid < NB_SCAN) ? bsum[tid] : 0;
    sh[tid] = v;
    __syncthreads();
    #pragma unroll
    for (int off = 1; off < 256; off <<= 1) {
        int t = (tid >= off) ? sh[tid - off] : 0;
        __syncthreads();
        sh[tid] += t;
        __syncthreads();
    }
    if (tid < NB_SCAN) bsum[tid] = sh[tid] - v;
}

__global__ __launch_bounds__(256) void scan3_kernel(const int* __restrict__ bsum,
                                                    int* __restrict__ rowptr,
                                                    int* __restrict__ cursor)
{
    int i = blockIdx.x * 256 + threadIdx.x;
    if (i < N_NODES) {
        int v = rowptr[i] + bsum[blockIdx.x];
        rowptr[i] = v;
        cursor[i] = v;
    }
    if (i == 0) rowptr[N_NODES] = N_EDGES;
}

// scatter packed (src<<16)|fp16(w) — 4B per edge (halves random-write bytes, R11: 52MB WRITE)
__global__ __launch_bounds__(256) void scatter_kernel(const int* __restrict__ ei,
                                                      const float* __restrict__ ew,
                                                      int* __restrict__ cursor,
                                                      unsigned* __restrict__ csr)
{
    int e = blockIdx.x * 256 + threadIdx.x;
    int dst = ei[N_EDGES + e];
    int pos = atomicAdd(&cursor[dst], 1);
    csr[pos] = ((unsigned)ei[e] << 16) | (unsigned)f2h(ew[e]);
}

// ================= atomic-free aggregation (bf16 features, 4B csr) =================
__global__ __launch_bounds__(256) void aggr_kernel(const unsigned short* __restrict__ x,
                                                   const unsigned* __restrict__ csr,
                                                   const int* __restrict__ rowptr,
                                                   const float* __restrict__ We,
                                                   const float* __restrict__ be,
                                                   unsigned short* __restrict__ hout)
{
    int node = blockIdx.x * 4 + (threadIdx.x >> 6);
    int lane = threadIdx.x & 63;
    int c = lane * 2;
    float2 wev = *reinterpret_cast<const float2*>(&We[c]);
    float2 bev = *reinterpret_cast<const float2*>(&be[c]);
    int p = rowptr[node], p1 = rowptr[node + 1];
    unsigned sv = *reinterpret_cast<const unsigned*>(&x[(size_t)node * C + c]);
    float ax = b2f(sv & 0xffffu), ay = b2f(sv >> 16);
    for (; p + 4 <= p1; p += 4) {
        unsigned e0 = csr[p], e1 = csr[p + 1], e2 = csr[p + 2], e3 = csr[p + 3];
        float w0 = h2f((unsigned short)e0), w1 = h2f((unsigned short)e1);
        float w2 = h2f((unsigned short)e2), w3 = h2f((unsigned short)e3);
        unsigned g0 = *reinterpret_cast<const unsigned*>(&x[(size_t)(e0 >> 16) * C + c]);
        unsigned g1 = *reinterpret_cast<const unsigned*>(&x[(size_t)(e1 >> 16) * C + c]);
        unsigned g2 = *reinterpret_cast<const unsigned*>(&x[(size_t)(e2 >> 16) * C + c]);
        unsigned g3 = *reinterpret_cast<const unsigned*>(&x[(size_t)(e3 >> 16) * C + c]);
        float m;
        m = b2f(g0 & 0xffffu) + w0 * wev.x + bev.x; ax += fmaxf(m, 0.f);
        m = b2f(g0 >> 16)     + w0 * wev.y + bev.y; ay += fmaxf(m, 0.f);
        m = b2f(g1 & 0xffffu) + w1 * wev.x + bev.x; ax += fmaxf(m, 0.f);
        m = b2f(g1 >> 16)     + w1 * wev.y + bev.y; ay += fmaxf(m, 0.f);
        m = b2f(g2 & 0xffffu) + w2 * wev.x + bev.x; ax += fmaxf(m, 0.f);
        m = b2f(g2 >> 16)     + w2 * wev.y + bev.y; ay += fmaxf(m, 0.f);
        m = b2f(g3 & 0xffffu) + w3 * wev.x + bev.x; ax += fmaxf(m, 0.f);
        m = b2f(g3 >> 16)     + w3 * wev.y + bev.y; ay += fmaxf(m, 0.f);
    }
    for (; p < p1; ++p) {
        unsigned e0 = csr[p];
        float w0 = h2f((unsigned short)e0);
        unsigned g0 = *reinterpret_cast<const unsigned*>(&x[(size_t)(e0 >> 16) * C + c]);
        float m;
        m = b2f(g0 & 0xffffu) + w0 * wev.x + bev.x; ax += fmaxf(m, 0.f);
        m = b2f(g0 >> 16)     + w0 * wev.y + bev.y; ay += fmaxf(m, 0.f);
    }
    unsigned o = (unsigned)f2b(ax) | ((unsigned)f2b(ay) << 16);
    *reinterpret_cast<unsigned*>(&hout[(size_t)node * C + c]) = o;
}

// ================= MFMA bf16 GEMM, prefetch + sector-aligned epilogue + fused BN stats =================
// MODE 0: out = bf16(A@W.T + bias); accumulate column sum/sumsq -> gsum/gsq (replaces stats_kernel)
// MODE 1: a = relu(bf16(A)*scale+shift); out = bf16(relu(a@W.T + bias))
// MODE 2: like MODE 1 but atomicMax-pool f32 into pooled[batch[row]*C+col]
template<int MODE>
__global__ __launch_bounds__(256) void mgemm_kernel(
    const unsigned short* __restrict__ A,
    const unsigned short* __restrict__ Wb,
    const float* __restrict__ bias,
    const float* __restrict__ scale,
    const float* __restrict__ shift,
    const int* __restrict__ batch,
    unsigned short* __restrict__ outb,
    float* __restrict__ pooled,
    float* __restrict__ gsum,
    float* __restrict__ gsq)
{
    __shared__ __align__(16) unsigned short xpose[4][16][40];  // per-wave [16 rows][32+pad]
    const int wave = threadIdx.x >> 6;
    const int lane = threadIdx.x & 63;
    const int colbase = wave << 5;
    const int lr = lane & 15;
    const int lk = (lane >> 4) << 3;   // 0,8,16,24

    bs8 bf[2][4];
    #pragma unroll
    for (int ct = 0; ct < 2; ++ct)
        #pragma unroll
        for (int kc = 0; kc < 4; ++kc)
            bf[ct][kc] = *reinterpret_cast<const bs8*>(
                &Wb[(size_t)(colbase + ct * 16 + lr) * C + kc * 32 + lk]);

    const float bi0 = bias[colbase + lr];
    const float bi1 = bias[colbase + 16 + lr];

    float sc[4][8], sh[4][8];
    if (MODE >= 1) {
        #pragma unroll
        for (int kc = 0; kc < 4; ++kc)
            #pragma unroll
            for (int i = 0; i < 8; ++i) {
                sc[kc][i] = scale[kc * 32 + lk + i];
                sh[kc][i] = shift[kc * 32 + lk + i];
            }
    }

    float ssum0 = 0.f, ssq0 = 0.f, ssum1 = 0.f, ssq1 = 0.f;  // MODE 0 BN stats

    int s = blockIdx.x;
    bs8 raw[4];
    #pragma unroll
    for (int kc = 0; kc < 4; ++kc)
        raw[kc] = *reinterpret_cast<const bs8*>(
            &A[(size_t)(s * 16 + lr) * C + kc * 32 + lk]);

    while (true) {
        const int snext = s + gridDim.x;
        bs8 rawn[4];
        if (snext < N_STRIPES) {
            #pragma unroll
            for (int kc = 0; kc < 4; ++kc)
                rawn[kc] = *reinterpret_cast<const bs8*>(
                    &A[(size_t)(snext * 16 + lr) * C + kc * 32 + lk]);
        }

        bs8 af[4];
        #pragma unroll
        for (int kc = 0; kc < 4; ++kc) {
            if (MODE == 0) {
                af[kc] = raw[kc];
            } else {
                union { bs8 v; unsigned short u[8]; } pk;
                #pragma unroll
                for (int i = 0; i < 8; ++i) {
                    float f = b2f((unsigned)(unsigned short)raw[kc][i]);
                    pk.u[i] = f2b(fmaxf(f * sc[kc][i] + sh[kc][i], 0.f));
                }
                af[kc] = pk.v;
            }
        }

        f32x4 a0 = {0.f, 0.f, 0.f, 0.f};
        f32x4 a1 = {0.f, 0.f, 0.f, 0.f};
        #pragma unroll
        for (int kc = 0; kc < 4; ++kc) {
            a0 = __builtin_amdgcn_mfma_f32_16x16x32_bf16(af[kc], bf[0][kc], a0, 0, 0, 0);
            a1 = __builtin_amdgcn_mfma_f32_16x16x32_bf16(af[kc], bf[1][kc], a1, 0, 0, 0);
        }

        const int row0 = s << 4;
        if (MODE == 2) {
            const int orow = row0 + ((lane >> 4) << 2);
            float o0[4], o1[4];
            #pragma unroll
            for (int r = 0; r < 4; ++r) {
                o0[r] = fmaxf(a0[r] + bi0, 0.f);
                o1[r] = fmaxf(a1[r] + bi1, 0.f);
            }
            int gA = batch[orow], gB = batch[orow + 3];
            if (gA == gB) {
                float m0 = fmaxf(fmaxf(o0[0], o0[1]), fmaxf(o0[2], o0[3]));
                float m1 = fmaxf(fmaxf(o1[0], o1[1]), fmaxf(o1[2], o1[3]));
                atomicMax(reinterpret_cast<int*>(&pooled[(size_t)gA * C + colbase + lr]),
                          __float_as_int(m0));
                atomicMax(reinterpret_cast<int*>(&pooled[(size_t)gA * C + colbase + 16 + lr]),
                          __float_as_int(m1));
            } else {
                #pragma unroll
                for (int r = 0; r < 4; ++r) {
                    int g = batch[orow + r];
                    atomicMax(reinterpret_cast<int*>(&pooled[(size_t)g * C + colbase + lr]),
                              __float_as_int(o0[r]));
                    atomicMax(reinterpret_cast<int*>(&pooled[(size_t)g * C + colbase + 16 + lr]),
                              __float_as_int(o1[r]));
                }
            }
        } else {
            #pragma unroll
            for (int r = 0; r < 4; ++r) {
                int rl = ((lane >> 4) << 2) + r;
                float o0 = a0[r] + bi0;
                float o1 = a1[r] + bi1;
                if (MODE == 0) {
                    ssum0 += o0; ssq0 += o0 * o0;
                    ssum1 += o1; ssq1 += o1 * o1;
                } else {
                    o0 = fmaxf(o0, 0.f); o1 = fmaxf(o1, 0.f);
                }
                xpose[wave][rl][lr]      = f2b(o0);
                xpose[wave][rl][lr + 16] = f2b(o1);
            }
            __builtin_amdgcn_sched_barrier(0);
            us8 v = *reinterpret_cast<const us8*>(&xpose[wave][lane >> 2][(lane & 3) * 8]);
            *reinterpret_cast<us8*>(
                &outb[(size_t)(row0 + (lane >> 2)) * C + colbase + (lane & 3) * 8]) = v;
            __builtin_amdgcn_sched_barrier(0);
        }

        if (snext >= N_STRIPES) break;
        #pragma unroll
        for (int kc = 0; kc < 4; ++kc) raw[kc] = rawn[kc];
        s = snext;
    }

    if (MODE == 0) {
        // reduce over the 4 row-groups (lanes lr, lr+16, lr+32, lr+48), then 4 atomics/wave
        ssum0 += __shfl_xor(ssum0, 16); ssum0 += __shfl_xor(ssum0, 32);
        ssq0  += __shfl_xor(ssq0, 16);  ssq0  += __shfl_xor(ssq0, 32);
        ssum1 += __shfl_xor(ssum1, 16); ssum1 += __shfl_xor(ssum1, 32);
        ssq1  += __shfl_xor(ssq1, 16);  ssq1  += __shfl_xor(ssq1, 32);
        if (lane < 16) {
            unsafeAtomicAdd(&gsum[colbase + lr], ssum0);
            unsafeAtomicAdd(&gsq[colbase + lr], ssq0);
            unsafeAtomicAdd(&gsum[colbase + 16 + lr], ssum1);
            unsafeAtomicAdd(&gsq[colbase + 16 + lr], ssq1);
        }
    }
}

__global__ void bnfin_kernel(const float* __restrict__ gsum, const float* __restrict__ gsq,
                             const float* __restrict__ g, const float* __restrict__ bt,
                             float* __restrict__ scale, float* __restrict__ shift)
{
    int c = threadIdx.x;
    float mu  = gsum[c] * (1.f / N_NODES);
    float var = gsq[c] * (1.f / N_NODES) - mu * mu;
    float rs  = rsqrtf(var + BN_EPS);
    float s   = rs * g[c];
    scale[c] = s;
    shift[c] = bt[c] - mu * s;
}

// ================= final linear (f32 pooled) =================
__global__ __launch_bounds__(64) void final_kernel(const float* __restrict__ pooled,
                                                   const float* __restrict__ lw,
                                                   const float* __restrict__ lb,
                                                   float* __restrict__ out)
{
    int gph = blockIdx.x;
    int lane = threadIdx.x;
    float v0 = pooled[(size_t)gph * C + lane];
    float v1 = pooled[(size_t)gph * C + lane + 64];
    for (int o = 0; o < OUTDIM; ++o) {
        float p = v0 * lw[o * C + lane] + v1 * lw[o * C + lane + 64];
        #pragma unroll
        for (int off = 32; off > 0; off >>= 1) p += __shfl_down(p, off);
        if (lane == 0) out[gph * OUTDIM + o] = p + lb[o];
    }
}

extern "C" void kernel_launch(void* const* d_in, const int* in_sizes, int n_in,
                              void* d_out, int out_size, void* d_ws, size_t ws_size,
                              hipStream_t stream)
{
    const float* x0   = (const float*)d_in[0];
    const int*   ei   = (const int*)  d_in[1];
    const float* ew   = (const float*)d_in[2];
    const int*   batch= (const int*)  d_in[3];
    const float* We0  = (const float*)d_in[4];
    const float* be0  = (const float*)d_in[5];
    const float* W1_0 = (const float*)d_in[6];
    const float* b1_0 = (const float*)d_in[7];
    const float* g0   = (const float*)d_in[8];
    const float* bt0  = (const float*)d_in[9];
    const float* W2_0 = (const float*)d_in[10];
    const float* b2_0 = (const float*)d_in[11];
    const float* We1  = (const float*)d_in[12];
    const float* be1  = (const float*)d_in[13];
    const float* W1_1 = (const float*)d_in[14];
    const float* b1_1 = (const float*)d_in[15];
    const float* g1   = (const float*)d_in[16];
    const float* bt1  = (const float*)d_in[17];
    const float* W2_1 = (const float*)d_in[18];
    const float* b2_1 = (const float*)d_in[19];
    const float* lin_w= (const float*)d_in[20];
    const float* lin_b= (const float*)d_in[21];

    char* base = (char*)d_ws;
    unsigned short* xb = (unsigned short*)(base);              // 12.8 MB  bf16 x0
    unsigned short* hA = (unsigned short*)(base + 12800000);   // 12.8 MB  h
    unsigned short* tB = (unsigned short*)(base + 25600000);   // 12.8 MB  t
    unsigned short* xC = (unsigned short*)(base + 38400000);   // 12.8 MB  x1
    unsigned short* Wb = (unsigned short*)(base + 51200000);   // 4 x 32 KB bf16 W
    unsigned* csr  = (unsigned*)(base + 51400000);             // 3.2 MB (4B/edge)
    int*    deg    = (int*)(base + 57800000);                  // 200 KB
    int*    rowptr = (int*)(base + 58000000);                  // 200 KB
    int*    cursor = (int*)(base + 58200008);                  // 200 KB
    int*    bsum   = (int*)(base + 58400008);                  // ~1 KB
    float*  gsum   = (float*)(base + 58401024);
    float*  gsq    = gsum + 128;
    float*  scale  = gsq + 128;
    float*  shift  = scale + 128;
    float*  pooled = (float*)(base + 58403072);                // 256 KB

    // ---- convert x0 + all four weight matrices to bf16
    conv_kernel<<<6250, 256, 0, stream>>>(x0, xb, N_NODES * C / 4);
    convw_kernel<<<64, 256, 0, stream>>>(W1_0, W2_0, W1_1, W2_1, Wb);

    // ---- build CSR once
    hipMemsetAsync(deg, 0, N_NODES * sizeof(int), stream);
    hist_kernel<<<N_EDGES / 256, 256, 0, stream>>>(ei, deg);
    scan1_kernel<<<NB_SCAN, 256, 0, stream>>>(deg, rowptr, bsum);
    scan2_kernel<<<1, 256, 0, stream>>>(bsum);
    scan3_kernel<<<NB_SCAN, 256, 0, stream>>>(bsum, rowptr, cursor);
    scatter_kernel<<<N_EDGES / 256, 256, 0, stream>>>(ei, ew, cursor, csr);

    // ---- layer 1
    aggr_kernel<<<N_NODES / 4, 256, 0, stream>>>(xb, csr, rowptr, We0, be0, hA);
    hipMemsetAsync(gsum, 0, 256 * sizeof(float), stream);
    mgemm_kernel<0><<<768, 256, 0, stream>>>(hA, Wb + 0 * 16384, b1_0,
                                             nullptr, nullptr, nullptr, tB, nullptr, gsum, gsq);
    bnfin_kernel<<<1, 128, 0, stream>>>(gsum, gsq, g0, bt0, scale, shift);
    mgemm_kernel<1><<<768, 256, 0, stream>>>(tB, Wb + 1 * 16384, b2_0,
                                             scale, shift, nullptr, xC, nullptr, nullptr, nullptr);

    // ---- layer 2
    aggr_kernel<<<N_NODES / 4, 256, 0, stream>>>(xC, csr, rowptr, We1, be1, hA);
    hipMemsetAsync(gsum, 0, 256 * sizeof(float), stream);
    mgemm_kernel<0><<<768, 256, 0, stream>>>(hA, Wb + 2 * 16384, b1_1,
                                             nullptr, nullptr, nullptr, tB, nullptr, gsum, gsq);
    bnfin_kernel<<<1, 128, 0, stream>>>(gsum, gsq, g1, bt1, scale, shift);
    hipMemsetAsync(pooled, 0, (size_t)N_GRAPHS * C * sizeof(float), stream);
    mgemm_kernel<2><<<768, 256, 0, stream>>>(tB, Wb + 3 * 16384, b2_1,
                                             scale, shift, batch, nullptr, pooled, nullptr, nullptr);

    // ---- final linear
    final_kernel<<<N_GRAPHS, 64, 0, stream>>>(pooled, lin_w, lin_b, (float*)d_out);
}

// Round 13
// 384.562 us; speedup vs baseline: 1.6162x; 1.0360x over previous
//
#include <hip/hip_runtime.h>

#define N_NODES 50000
#define N_EDGES 800000
#define C 128
#define N_GRAPHS 512
#define OUTDIM 5
#define BN_EPS 1e-5f
#define NB_SCAN 196      // ceil(50000/256)
#define N_STRIPES 3125   // 50000/16 exact
#define SCAT_SUB 100     // subgrids per XCD slice; grid = 8*SCAT_SUB

typedef short bs8 __attribute__((ext_vector_type(8)));   // 8 bf16 (4 VGPR) MFMA operand
typedef float f32x4 __attribute__((ext_vector_type(4))); // MFMA accumulator
typedef unsigned short us8 __attribute__((ext_vector_type(8)));

__device__ __forceinline__ unsigned short f2b(float f) {  // f32 -> bf16 RNE
    unsigned u = __float_as_uint(f);
    u += 0x7fffu + ((u >> 16) & 1u);
    return (unsigned short)(u >> 16);
}
__device__ __forceinline__ float b2f(unsigned v) {        // bf16 bits -> f32
    return __uint_as_float(v << 16);
}
__device__ __forceinline__ unsigned short f2h(float f) {  // f32 -> fp16 bits
    union { _Float16 h; unsigned short s; } cv;
    cv.h = (_Float16)f;
    return cv.s;
}
__device__ __forceinline__ float h2f(unsigned short s) {  // fp16 bits -> f32
    union { unsigned short s; _Float16 h; } cv;
    cv.s = s;
    return (float)cv.h;
}

// ================= f32 -> bf16 conversion (x0) =================
__global__ __launch_bounds__(256) void conv_kernel(const float* __restrict__ in,
                                                   unsigned short* __restrict__ out, int n4)
{
    int i = blockIdx.x * 256 + threadIdx.x;
    if (i < n4) {
        float4 v = reinterpret_cast<const float4*>(in)[i];
        ushort4 o;
        o.x = f2b(v.x); o.y = f2b(v.y); o.z = f2b(v.z); o.w = f2b(v.w);
        reinterpret_cast<ushort4*>(out)[i] = o;
    }
}

// all four 128x128 weight matrices in one launch (64 blocks; 16 per matrix)
__global__ __launch_bounds__(256) void convw_kernel(const float* __restrict__ w0,
                                                    const float* __restrict__ w1,
                                                    const float* __restrict__ w2,
                                                    const float* __restrict__ w3,
                                                    unsigned short* __restrict__ out)
{
    const float* src[4] = {w0, w1, w2, w3};
    int m = blockIdx.x >> 4;
    int i = (blockIdx.x & 15) * 256 + threadIdx.x;   // 0..4095 float4
    float4 v = reinterpret_cast<const float4*>(src[m])[i];
    ushort4 o;
    o.x = f2b(v.x); o.y = f2b(v.y); o.z = f2b(v.z); o.w = f2b(v.w);
    reinterpret_cast<ushort4*>(out + m * 16384)[i] = o;
}

// ================= CSR build =================
__global__ __launch_bounds__(256) void hist_kernel(const int* __restrict__ ei,
                                                   int* __restrict__ deg)
{
    int e = blockIdx.x * 256 + threadIdx.x;
    atomicAdd(&deg[ei[N_EDGES + e]], 1);
}

__global__ __launch_bounds__(256) void scan1_kernel(const int* __restrict__ deg,
                                                    int* __restrict__ rowptr,
                                                    int* __restrict__ bsum)
{
    __shared__ int sh[256];
    int tid = threadIdx.x;
    int i = blockIdx.x * 256 + tid;
    int v = (i < N_NODES) ? deg[i] : 0;
    sh[tid] = v;
    __syncthreads();
    #pragma unroll
    for (int off = 1; off < 256; off <<= 1) {
        int t = (tid >= off) ? sh[tid - off] : 0;
        __syncthreads();
        sh[tid] += t;
        __syncthreads();
    }
    if (i < N_NODES) rowptr[i] = sh[tid] - v;
    if (tid == 255) bsum[blockIdx.x] = sh[255];
}

__global__ __launch_bounds__(256) void scan2_kernel(int* __restrict__ bsum)
{
    __shared__ int sh[256];
    int tid = threadIdx.x;
    int v = (tid < NB_SCAN) ? bsum[tid] : 0;
    sh[tid] = v;
    __syncthreads();
    #pragma unroll
    for (int off = 1; off < 256; off <<= 1) {
        int t = (tid >= off) ? sh[tid - off] : 0;
        __syncthreads();
        sh[tid] += t;
        __syncthreads();
    }
    if (tid < NB_SCAN) bsum[tid] = sh[tid] - v;
}

__global__ __launch_bounds__(256) void scan3_kernel(const int* __restrict__ bsum,
                                                    int* __restrict__ rowptr,
                                                    int* __restrict__ cursor)
{
    int i = blockIdx.x * 256 + threadIdx.x;
    if (i < N_NODES) {
        int v = rowptr[i] + bsum[blockIdx.x];
        rowptr[i] = v;
        cursor[i] = v;
    }
    if (i == 0) rowptr[N_NODES] = N_EDGES;
}

// XCD-partitioned scatter: block b handles dst slice (b&7); round-robin blockIdx->XCD
// means each csr sector is written by ONE XCD's L2 only -> full-line merge before
// writeback (fix for R12: 54MB WRITE = 1 sector/access, cross-XCD false sharing).
__global__ __launch_bounds__(256) void scatter_kernel(const int* __restrict__ ei,
                                                      const float* __restrict__ ew,
                                                      int* __restrict__ cursor,
                                                      unsigned* __restrict__ csr)
{
    const int r   = blockIdx.x & 7;              // presumed XCD (perf heuristic only)
    const int sub = blockIdx.x >> 3;             // 0..SCAT_SUB-1
    const int lo  = r * (N_NODES / 8);
    const int hi  = lo + (N_NODES / 8);
    for (int e = sub * 256 + threadIdx.x; e < N_EDGES; e += SCAT_SUB * 256) {
        int dst = ei[N_EDGES + e];
        if (dst >= lo && dst < hi) {
            int pos = atomicAdd(&cursor[dst], 1);
            csr[pos] = ((unsigned)ei[e] << 16) | (unsigned)f2h(ew[e]);
        }
    }
}

// ================= atomic-free aggregation (bf16 features, 4B csr) =================
__global__ __launch_bounds__(256) void aggr_kernel(const unsigned short* __restrict__ x,
                                                   const unsigned* __restrict__ csr,
                                                   const int* __restrict__ rowptr,
                                                   const float* __restrict__ We,
                                                   const float* __restrict__ be,
                                                   unsigned short* __restrict__ hout)
{
    int node = blockIdx.x * 4 + (threadIdx.x >> 6);
    int lane = threadIdx.x & 63;
    int c = lane * 2;
    float2 wev = *reinterpret_cast<const float2*>(&We[c]);
    float2 bev = *reinterpret_cast<const float2*>(&be[c]);
    int p = rowptr[node], p1 = rowptr[node + 1];
    unsigned sv = *reinterpret_cast<const unsigned*>(&x[(size_t)node * C + c]);
    float ax = b2f(sv & 0xffffu), ay = b2f(sv >> 16);
    for (; p + 4 <= p1; p += 4) {
        unsigned e0 = csr[p], e1 = csr[p + 1], e2 = csr[p + 2], e3 = csr[p + 3];
        float w0 = h2f((unsigned short)e0), w1 = h2f((unsigned short)e1);
        float w2 = h2f((unsigned short)e2), w3 = h2f((unsigned short)e3);
        unsigned g0 = *reinterpret_cast<const unsigned*>(&x[(size_t)(e0 >> 16) * C + c]);
        unsigned g1 = *reinterpret_cast<const unsigned*>(&x[(size_t)(e1 >> 16) * C + c]);
        unsigned g2 = *reinterpret_cast<const unsigned*>(&x[(size_t)(e2 >> 16) * C + c]);
        unsigned g3 = *reinterpret_cast<const unsigned*>(&x[(size_t)(e3 >> 16) * C + c]);
        float m;
        m = b2f(g0 & 0xffffu) + w0 * wev.x + bev.x; ax += fmaxf(m, 0.f);
        m = b2f(g0 >> 16)     + w0 * wev.y + bev.y; ay += fmaxf(m, 0.f);
        m = b2f(g1 & 0xffffu) + w1 * wev.x + bev.x; ax += fmaxf(m, 0.f);
        m = b2f(g1 >> 16)     + w1 * wev.y + bev.y; ay += fmaxf(m, 0.f);
        m = b2f(g2 & 0xffffu) + w2 * wev.x + bev.x; ax += fmaxf(m, 0.f);
        m = b2f(g2 >> 16)     + w2 * wev.y + bev.y; ay += fmaxf(m, 0.f);
        m = b2f(g3 & 0xffffu) + w3 * wev.x + bev.x; ax += fmaxf(m, 0.f);
        m = b2f(g3 >> 16)     + w3 * wev.y + bev.y; ay += fmaxf(m, 0.f);
    }
    for (; p < p1; ++p) {
        unsigned e0 = csr[p];
        float w0 = h2f((unsigned short)e0);
        unsigned g0 = *reinterpret_cast<const unsigned*>(&x[(size_t)(e0 >> 16) * C + c]);
        float m;
        m = b2f(g0 & 0xffffu) + w0 * wev.x + bev.x; ax += fmaxf(m, 0.f);
        m = b2f(g0 >> 16)     + w0 * wev.y + bev.y; ay += fmaxf(m, 0.f);
    }
    unsigned o = (unsigned)f2b(ax) | ((unsigned)f2b(ay) << 16);
    *reinterpret_cast<unsigned*>(&hout[(size_t)node * C + c]) = o;
}

// ================= MFMA bf16 GEMM, prefetch + sector-aligned epilogue + fused BN stats =================
// MODE 0: out = bf16(A@W.T + bias); accumulate column sum/sumsq -> gsum/gsq
// MODE 1: a = relu(bf16(A)*scale+shift); out = bf16(relu(a@W.T + bias))
// MODE 2: like MODE 1 but atomicMax-pool f32 into pooled[batch[row]*C+col]
template<int MODE>
__global__ __launch_bounds__(256) void mgemm_kernel(
    const unsigned short* __restrict__ A,
    const unsigned short* __restrict__ Wb,
    const float* __restrict__ bias,
    const float* __restrict__ scale,
    const float* __restrict__ shift,
    const int* __restrict__ batch,
    unsigned short* __restrict__ outb,
    float* __restrict__ pooled,
    float* __restrict__ gsum,
    float* __restrict__ gsq)
{
    __shared__ __align__(16) unsigned short xpose[4][16][40];  // per-wave [16 rows][32+pad]
    const int wave = threadIdx.x >> 6;
    const int lane = threadIdx.x & 63;
    const int colbase = wave << 5;
    const int lr = lane & 15;
    const int lk = (lane >> 4) << 3;   // 0,8,16,24

    bs8 bf[2][4];
    #pragma unroll
    for (int ct = 0; ct < 2; ++ct)
        #pragma unroll
        for (int kc = 0; kc < 4; ++kc)
            bf[ct][kc] = *reinterpret_cast<const bs8*>(
                &Wb[(size_t)(colbase + ct * 16 + lr) * C + kc * 32 + lk]);

    const float bi0 = bias[colbase + lr];
    const float bi1 = bias[colbase + 16 + lr];

    float sc[4][8], sh[4][8];
    if (MODE >= 1) {
        #pragma unroll
        for (int kc = 0; kc < 4; ++kc)
            #pragma unroll
            for (int i = 0; i < 8; ++i) {
                sc[kc][i] = scale[kc * 32 + lk + i];
                sh[kc][i] = shift[kc * 32 + lk + i];
            }
    }

    float ssum0 = 0.f, ssq0 = 0.f, ssum1 = 0.f, ssq1 = 0.f;  // MODE 0 BN stats

    int s = blockIdx.x;
    bs8 raw[4];
    #pragma unroll
    for (int kc = 0; kc < 4; ++kc)
        raw[kc] = *reinterpret_cast<const bs8*>(
            &A[(size_t)(s * 16 + lr) * C + kc * 32 + lk]);

    while (true) {
        const int snext = s + gridDim.x;
        bs8 rawn[4];
        if (snext < N_STRIPES) {
            #pragma unroll
            for (int kc = 0; kc < 4; ++kc)
                rawn[kc] = *reinterpret_cast<const bs8*>(
                    &A[(size_t)(snext * 16 + lr) * C + kc * 32 + lk]);
        }

        bs8 af[4];
        #pragma unroll
        for (int kc = 0; kc < 4; ++kc) {
            if (MODE == 0) {
                af[kc] = raw[kc];
            } else {
                union { bs8 v; unsigned short u[8]; } pk;
                #pragma unroll
                for (int i = 0; i < 8; ++i) {
                    float f = b2f((unsigned)(unsigned short)raw[kc][i]);
                    pk.u[i] = f2b(fmaxf(f * sc[kc][i] + sh[kc][i], 0.f));
                }
                af[kc] = pk.v;
            }
        }

        f32x4 a0 = {0.f, 0.f, 0.f, 0.f};
        f32x4 a1 = {0.f, 0.f, 0.f, 0.f};
        #pragma unroll
        for (int kc = 0; kc < 4; ++kc) {
            a0 = __builtin_amdgcn_mfma_f32_16x16x32_bf16(af[kc], bf[0][kc], a0, 0, 0, 0);
            a1 = __builtin_amdgcn_mfma_f32_16x16x32_bf16(af[kc], bf[1][kc], a1, 0, 0, 0);
        }

        const int row0 = s << 4;
        if (MODE == 2) {
            const int orow = row0 + ((lane >> 4) << 2);
            float o0[4], o1[4];
            #pragma unroll
            for (int r = 0; r < 4; ++r) {
                o0[r] = fmaxf(a0[r] + bi0, 0.f);
                o1[r] = fmaxf(a1[r] + bi1, 0.f);
            }
            int gA = batch[orow], gB = batch[orow + 3];
            if (gA == gB) {
                float m0 = fmaxf(fmaxf(o0[0], o0[1]), fmaxf(o0[2], o0[3]));
                float m1 = fmaxf(fmaxf(o1[0], o1[1]), fmaxf(o1[2], o1[3]));
                atomicMax(reinterpret_cast<int*>(&pooled[(size_t)gA * C + colbase + lr]),
                          __float_as_int(m0));
                atomicMax(reinterpret_cast<int*>(&pooled[(size_t)gA * C + colbase + 16 + lr]),
                          __float_as_int(m1));
            } else {
                #pragma unroll
                for (int r = 0; r < 4; ++r) {
                    int g = batch[orow + r];
                    atomicMax(reinterpret_cast<int*>(&pooled[(size_t)g * C + colbase + lr]),
                              __float_as_int(o0[r]));
                    atomicMax(reinterpret_cast<int*>(&pooled[(size_t)g * C + colbase + 16 + lr]),
                              __float_as_int(o1[r]));
                }
            }
        } else {
            #pragma unroll
            for (int r = 0; r < 4; ++r) {
                int rl = ((lane >> 4) << 2) + r;
                float o0 = a0[r] + bi0;
                float o1 = a1[r] + bi1;
                if (MODE == 0) {
                    ssum0 += o0; ssq0 += o0 * o0;
                    ssum1 += o1; ssq1 += o1 * o1;
                } else {
                    o0 = fmaxf(o0, 0.f); o1 = fmaxf(o1, 0.f);
                }
                xpose[wave][rl][lr]      = f2b(o0);
                xpose[wave][rl][lr + 16] = f2b(o1);
            }
            __builtin_amdgcn_sched_barrier(0);
            us8 v = *reinterpret_cast<const us8*>(&xpose[wave][lane >> 2][(lane & 3) * 8]);
            *reinterpret_cast<us8*>(
                &outb[(size_t)(row0 + (lane >> 2)) * C + colbase + (lane & 3) * 8]) = v;
            __builtin_amdgcn_sched_barrier(0);
        }

        if (snext >= N_STRIPES) break;
        #pragma unroll
        for (int kc = 0; kc < 4; ++kc) raw[kc] = rawn[kc];
        s = snext;
    }

    if (MODE == 0) {
        ssum0 += __shfl_xor(ssum0, 16); ssum0 += __shfl_xor(ssum0, 32);
        ssq0  += __shfl_xor(ssq0, 16);  ssq0  += __shfl_xor(ssq0, 32);
        ssum1 += __shfl_xor(ssum1, 16); ssum1 += __shfl_xor(ssum1, 32);
        ssq1  += __shfl_xor(ssq1, 16);  ssq1  += __shfl_xor(ssq1, 32);
        if (lane < 16) {
            unsafeAtomicAdd(&gsum[colbase + lr], ssum0);
            unsafeAtomicAdd(&gsq[colbase + lr], ssq0);
            unsafeAtomicAdd(&gsum[colbase + 16 + lr], ssum1);
            unsafeAtomicAdd(&gsq[colbase + 16 + lr], ssq1);
        }
    }
}

__global__ void bnfin_kernel(const float* __restrict__ gsum, const float* __restrict__ gsq,
                             const float* __restrict__ g, const float* __restrict__ bt,
                             float* __restrict__ scale, float* __restrict__ shift)
{
    int c = threadIdx.x;
    float mu  = gsum[c] * (1.f / N_NODES);
    float var = gsq[c] * (1.f / N_NODES) - mu * mu;
    float rs  = rsqrtf(var + BN_EPS);
    float s   = rs * g[c];
    scale[c] = s;
    shift[c] = bt[c] - mu * s;
}

// ================= final linear (f32 pooled) =================
__global__ __launch_bounds__(64) void final_kernel(const float* __restrict__ pooled,
                                                   const float* __restrict__ lw,
                                                   const float* __restrict__ lb,
                                                   float* __restrict__ out)
{
    int gph = blockIdx.x;
    int lane = threadIdx.x;
    float v0 = pooled[(size_t)gph * C + lane];
    float v1 = pooled[(size_t)gph * C + lane + 64];
    for (int o = 0; o < OUTDIM; ++o) {
        float p = v0 * lw[o * C + lane] + v1 * lw[o * C + lane + 64];
        #pragma unroll
        for (int off = 32; off > 0; off >>= 1) p += __shfl_down(p, off);
        if (lane == 0) out[gph * OUTDIM + o] = p + lb[o];
    }
}

extern "C" void kernel_launch(void* const* d_in, const int* in_sizes, int n_in,
                              void* d_out, int out_size, void* d_ws, size_t ws_size,
                              hipStream_t stream)
{
    const float* x0   = (const float*)d_in[0];
    const int*   ei   = (const int*)  d_in[1];
    const float* ew   = (const float*)d_in[2];
    const int*   batch= (const int*)  d_in[3];
    const float* We0  = (const float*)d_in[4];
    const float* be0  = (const float*)d_in[5];
    const float* W1_0 = (const float*)d_in[6];
    const float* b1_0 = (const float*)d_in[7];
    const float* g0   = (const float*)d_in[8];
    const float* bt0  = (const float*)d_in[9];
    const float* W2_0 = (const float*)d_in[10];
    const float* b2_0 = (const float*)d_in[11];
    const float* We1  = (const float*)d_in[12];
    const float* be1  = (const float*)d_in[13];
    const float* W1_1 = (const float*)d_in[14];
    const float* b1_1 = (const float*)d_in[15];
    const float* g1   = (const float*)d_in[16];
    const float* bt1  = (const float*)d_in[17];
    const float* W2_1 = (const float*)d_in[18];
    const float* b2_1 = (const float*)d_in[19];
    const float* lin_w= (const float*)d_in[20];
    const float* lin_b= (const float*)d_in[21];

    char* base = (char*)d_ws;
    unsigned short* xb = (unsigned short*)(base);              // 12.8 MB  bf16 x0
    unsigned short* hA = (unsigned short*)(base + 12800000);   // 12.8 MB  h
    unsigned short* tB = (unsigned short*)(base + 25600000);   // 12.8 MB  t
    unsigned short* xC = (unsigned short*)(base + 38400000);   // 12.8 MB  x1
    unsigned short* Wb = (unsigned short*)(base + 51200000);   // 4 x 32 KB bf16 W
    unsigned* csr  = (unsigned*)(base + 51400000);             // 3.2 MB (4B/edge)
    int*    deg    = (int*)(base + 57800000);                  // 200 KB
    int*    rowptr = (int*)(base + 58000000);                  // 200 KB
    int*    cursor = (int*)(base + 58200008);                  // 200 KB
    int*    bsum   = (int*)(base + 58400008);                  // ~1 KB
    float*  gsum   = (float*)(base + 58401024);
    float*  gsq    = gsum + 128;
    float*  scale  = gsq + 128;
    float*  shift  = scale + 128;
    float*  pooled = (float*)(base + 58403072);                // 256 KB

    // ---- convert x0 + all four weight matrices to bf16
    conv_kernel<<<6250, 256, 0, stream>>>(x0, xb, N_NODES * C / 4);
    convw_kernel<<<64, 256, 0, stream>>>(W1_0, W2_0, W1_1, W2_1, Wb);

    // ---- build CSR once
    hipMemsetAsync(deg, 0, N_NODES * sizeof(int), stream);
    hist_kernel<<<N_EDGES / 256, 256, 0, stream>>>(ei, deg);
    scan1_kernel<<<NB_SCAN, 256, 0, stream>>>(deg, rowptr, bsum);
    scan2_kernel<<<1, 256, 0, stream>>>(bsum);
    scan3_kernel<<<NB_SCAN, 256, 0, stream>>>(bsum, rowptr, cursor);
    scatter_kernel<<<SCAT_SUB * 8, 256, 0, stream>>>(ei, ew, cursor, csr);

    // ---- layer 1
    aggr_kernel<<<N_NODES / 4, 256, 0, stream>>>(xb, csr, rowptr, We0, be0, hA);
    hipMemsetAsync(gsum, 0, 256 * sizeof(float), stream);
    mgemm_kernel<0><<<768, 256, 0, stream>>>(hA, Wb + 0 * 16384, b1_0,
                                             nullptr, nullptr, nullptr, tB, nullptr, gsum, gsq);
    bnfin_kernel<<<1, 128, 0, stream>>>(gsum, gsq, g0, bt0, scale, shift);
    mgemm_kernel<1><<<768, 256, 0, stream>>>(tB, Wb + 1 * 16384, b2_0,
                                             scale, shift, nullptr, xC, nullptr, nullptr, nullptr);

    // ---- layer 2
    aggr_kernel<<<N_NODES / 4, 256, 0, stream>>>(xC, csr, rowptr, We1, be1, hA);
    hipMemsetAsync(gsum, 0, 256 * sizeof(float), stream);
    mgemm_kernel<0><<<768, 256, 0, stream>>>(hA, Wb + 2 * 16384, b1_1,
                                             nullptr, nullptr, nullptr, tB, nullptr, gsum, gsq);
    bnfin_kernel<<<1, 128, 0, stream>>>(gsum, gsq, g1, bt1, scale, shift);
    hipMemsetAsync(pooled, 0, (size_t)N_GRAPHS * C * sizeof(float), stream);
    mgemm_kernel<2><<<768, 256, 0, stream>>>(tB, Wb + 3 * 16384, b2_1,
                                             scale, shift, batch, nullptr, pooled, nullptr, nullptr);

    // ---- final linear
    final_kernel<<<N_GRAPHS, 64, 0, stream>>>(pooled, lin_w, lin_b, (float*)d_out);
}